// Round 1
// baseline (704.545 us; speedup 1.0000x reference)
//
#include <hip/hip_runtime.h>
#include <math.h>

#define NPIX 262144   // 512*512
#define NKER 15
#define PI_F 3.14159265358979323846f

__device__ __forceinline__ float2 cmul(float2 a, float2 b) {
  return make_float2(a.x * b.x - a.y * b.y, a.x * b.y + a.y * b.x);
}

// twiddle table: tw[u] = e^{-2*pi*i*u/512}, u = 0..255
__device__ __forceinline__ void build_tw(float2* tw, int tid) {
  for (int u = tid; u < 256; u += 64) {
    float s, c;
    sincosf(-2.0f * PI_F * (float)u / 512.0f, &s, &c);
    tw[u] = make_float2(c, s);
  }
}

// Stockham radix-2 DIF, 512 points, 64 threads, ping-pong LDS buffers.
// Data starts in s; returns pointer to the buffer holding the result.
// inv=true gives UNSCALED inverse (conjugate twiddles).
__device__ __forceinline__ float2* fft512(float2* s, float2* d, const float2* tw,
                                          int tid, bool inv) {
#pragma unroll
  for (int stage = 0; stage < 9; ++stage) {
    const int m = 1 << stage;
    __syncthreads();
#pragma unroll
    for (int u = 0; u < 4; ++u) {
      int i = tid + (u << 6);        // 0..255
      int jm = i & ~(m - 1);         // j*m
      float2 c0 = s[i];
      float2 c1 = s[i + 256];
      float2 w = tw[jm];
      float wy = inv ? -w.y : w.y;
      float drx = c0.x - c1.x, dry = c0.y - c1.y;
      d[i + jm] = make_float2(c0.x + c1.x, c0.y + c1.y);
      d[i + jm + m] = make_float2(w.x * drx - wy * dry, w.x * dry + wy * drx);
    }
    float2* t = s; s = d; d = t;
  }
  __syncthreads();
  return s;
}

// scales[k] = 1 / (sum(Ks[:,:,k]) * 512*512)   (folds ifft2 1/N^2 into fk)
__global__ void ksum_kernel(const float* __restrict__ Ks, float* __restrict__ scales) {
  __shared__ float red[256];
  int k = blockIdx.x, tid = threadIdx.x;
  float s = 0.f;
  for (int p = tid; p < NPIX; p += 256) s += Ks[(size_t)p * NKER + k];
  red[tid] = s;
  __syncthreads();
  for (int off = 128; off > 0; off >>= 1) {
    if (tid < off) red[tid] += red[tid + off];
    __syncthreads();
  }
  if (tid == 0) scales[k] = 1.0f / (red[0] * 262144.0f);
}

// forward row FFT of x channel c  -> Ax[c][row][y]
__global__ void fft_rows_x(const float* __restrict__ x, float2* __restrict__ Ax) {
  __shared__ float2 b0[512], b1[512], tw[256];
  int tid = threadIdx.x, row = blockIdx.x, c = blockIdx.y;
  build_tw(tw, tid);
  for (int u = 0; u < 8; ++u) {
    int y = tid + (u << 6);
    b0[y] = make_float2(x[((size_t)row * 512 + y) * 3 + c], 0.f);
  }
  float2* r = fft512(b0, b1, tw, tid, false);
  float2* dst = Ax + (size_t)c * NPIX + (size_t)row * 512;
  for (int u = 0; u < 8; ++u) { int y = tid + (u << 6); dst[y] = r[y]; }
}

// forward row FFT of fftshift(Ks[:,:,k]) * scales[k] -> Ak[k][row][y]
__global__ void fft_rows_k(const float* __restrict__ Ks, const float* __restrict__ scales,
                           float2* __restrict__ Ak) {
  __shared__ float2 b0[512], b1[512], tw[256];
  int tid = threadIdx.x, row = blockIdx.x, k = blockIdx.y;
  build_tw(tw, tid);
  float sc = scales[k];
  int rs = (row + 256) & 511;   // 2D fftshift folded into loads
  for (int u = 0; u < 8; ++u) {
    int y = tid + (u << 6);
    int ys = (y + 256) & 511;
    b0[y] = make_float2(Ks[((size_t)rs * 512 + ys) * NKER + k] * sc, 0.f);
  }
  float2* r = fft512(b0, b1, tw, tid, false);
  float2* dst = Ak + (size_t)k * NPIX + (size_t)row * 512;
  for (int u = 0; u < 8; ++u) { int y = tid + (u << 6); dst[y] = r[y]; }
}

// forward column FFT, in place; gridDim.y = #channels
__global__ void fft_cols_kernel(float2* __restrict__ A) {
  __shared__ float2 b0[512], b1[512], tw[256];
  int tid = threadIdx.x, col = blockIdx.x, ch = blockIdx.y;
  build_tw(tw, tid);
  float2* base = A + (size_t)ch * NPIX;
  for (int u = 0; u < 8; ++u) {
    int r = tid + (u << 6);
    b0[r] = base[(size_t)r * 512 + col];
  }
  float2* res = fft512(b0, b1, tw, tid, false);
  for (int u = 0; u < 8; ++u) {
    int r = tid + (u << 6);
    base[(size_t)r * 512 + col] = res[r];
  }
}

// inverse column FFT of (Ak[k] * Ax[c0[k]]), in place into Ak[k]
__global__ void ifft_cols_mul(float2* __restrict__ Ak, const float2* __restrict__ Ax,
                              const int* __restrict__ c0) {
  __shared__ float2 b0[512], b1[512], tw[256];
  int tid = threadIdx.x, col = blockIdx.x, k = blockIdx.y;
  build_tw(tw, tid);
  int c = c0[k];
  float2* bk = Ak + (size_t)k * NPIX;
  const float2* bx = Ax + (size_t)c * NPIX;
  for (int u = 0; u < 8; ++u) {
    int r = tid + (u << 6);
    size_t idx = (size_t)r * 512 + col;
    b0[r] = cmul(bk[idx], bx[idx]);
  }
  float2* res = fft512(b0, b1, tw, tid, true);
  for (int u = 0; u < 8; ++u) {
    int r = tid + (u << 6);
    bk[(size_t)r * 512 + col] = res[r];
  }
}

// inverse row FFT -> Us real -> growth -> Gs[k][row][y]  (Gs includes *h)
__global__ void ifft_rows_growth(const float2* __restrict__ Ak, const float* __restrict__ m,
                                 const float* __restrict__ s, const float* __restrict__ h,
                                 float* __restrict__ Gs) {
  __shared__ float2 b0[512], b1[512], tw[256];
  int tid = threadIdx.x, row = blockIdx.x, k = blockIdx.y;
  build_tw(tw, tid);
  const float2* src = Ak + (size_t)k * NPIX + (size_t)row * 512;
  for (int u = 0; u < 8; ++u) { int y = tid + (u << 6); b0[y] = src[y]; }
  float2* r = fft512(b0, b1, tw, tid, true);
  float mk = m[k], invs = 1.0f / s[k], hk = h[k];
  float* dst = Gs + (size_t)k * NPIX + (size_t)row * 512;
  for (int u = 0; u < 8; ++u) {
    int y = tid + (u << 6);
    float t = (r[y].x - mk) * invs;
    dst[y] = (expf(-0.5f * t * t) * 2.0f - 1.0f) * hk;
  }
}

// Hs[c][p] = sum_k Gs[k][p] * w_c1[k][c]
__global__ void combine_hs(const float* __restrict__ Gs, const float* __restrict__ w,
                           float* __restrict__ Hs) {
  int p = blockIdx.x * 256 + threadIdx.x;
  float a0 = 0.f, a1 = 0.f, a2 = 0.f;
#pragma unroll
  for (int k = 0; k < NKER; ++k) {
    float g = Gs[(size_t)k * NPIX + p];
    a0 += g * w[k * 3 + 0];
    a1 += g * w[k * 3 + 1];
    a2 += g * w[k * 3 + 2];
  }
  Hs[p] = a0; Hs[NPIX + p] = a1; Hs[2 * NPIX + p] = a2;
}

// sobel (zero pad) + alpha + F + mu.  mu layout: mu[p*6 + axis*3 + c]
__global__ void flow_kernel(const float* __restrict__ x, const float* __restrict__ Hs,
                            float* __restrict__ mu) {
  int p = blockIdx.x * 256 + threadIdx.x;
  int px = p >> 9, py = p & 511;
  float syH0 = 0.f, syH1 = 0.f, syH2 = 0.f;
  float sxH0 = 0.f, sxH1 = 0.f, sxH2 = 0.f;
  float syX = 0.f, sxX = 0.f;
#pragma unroll
  for (int di = -1; di <= 1; ++di) {
#pragma unroll
    for (int dj = -1; dj <= 1; ++dj) {
      if (di == 0 && dj == 0) continue;
      int xi = px + di, yj = py + dj;
      if ((unsigned)xi >= 512u || (unsigned)yj >= 512u) continue;  // zero pad
      float wy = (float)di * ((dj == 0) ? 2.f : 1.f);  // kx.T coeff (d/dx)
      float wx = (float)dj * ((di == 0) ? 2.f : 1.f);  // kx coeff (d/dy)
      int q = (xi << 9) | yj;
      float h0 = Hs[q], h1 = Hs[NPIX + q], h2 = Hs[2 * NPIX + q];
      syH0 += wy * h0; syH1 += wy * h1; syH2 += wy * h2;
      sxH0 += wx * h0; sxH1 += wx * h1; sxH2 += wx * h2;
      float xs = x[(size_t)q * 3 + 0] + x[(size_t)q * 3 + 1] + x[(size_t)q * 3 + 2];
      syX += wy * xs; sxX += wx * xs;
    }
  }
  float cxp = (float)px + 0.5f, cyp = (float)py + 0.5f;
  float* mup = mu + (size_t)p * 6;
  float syH[3] = {syH0, syH1, syH2};
  float sxH[3] = {sxH0, sxH1, sxH2};
#pragma unroll
  for (int c = 0; c < 3; ++c) {
    float xc = x[(size_t)p * 3 + c];
    float t = xc * 0.5f;                 // x / THETA_X
    float alpha = fminf(t * t, 1.0f);    // clip((x/2)^2, 0, 1)
    float F0 = syH[c] * (1.f - alpha) - syX * alpha;
    float F1 = sxH[c] * (1.f - alpha) - sxX * alpha;
    float m0 = cxp + fminf(fmaxf(0.2f * F0, -1.05f), 1.05f);
    float m1 = cyp + fminf(fmaxf(0.2f * F1, -1.05f), 1.05f);
    mup[c]     = fminf(fmaxf(m0, 0.95f), 511.05f);
    mup[3 + c] = fminf(fmaxf(m1, 0.95f), 511.05f);
  }
}

// 25-offset reintegration gather
__global__ void reintegrate_kernel(const float* __restrict__ x, const float* __restrict__ mu,
                                   float* __restrict__ out) {
  int p = blockIdx.x * 256 + threadIdx.x;
  int px = p >> 9, py = p & 511;
  float cx = (float)px + 0.5f, cy = (float)py + 0.5f;
  float a0 = 0.f, a1 = 0.f, a2 = 0.f;
#pragma unroll
  for (int dx = -2; dx <= 2; ++dx) {
    int qx = (px - dx + 512) & 511;
#pragma unroll
    for (int dy = -2; dy <= 2; ++dy) {
      int qy = (py - dy + 512) & 511;
      int q = (qx << 9) | qy;
      const float* muq = mu + (size_t)q * 6;
      const float* gq = x + (size_t)q * 3;
      float w;
      w = fminf(fmaxf(1.45f - fabsf(cx - muq[0]), 0.f), 1.f) *
          fminf(fmaxf(1.45f - fabsf(cy - muq[3]), 0.f), 1.f);
      a0 += gq[0] * w;
      w = fminf(fmaxf(1.45f - fabsf(cx - muq[1]), 0.f), 1.f) *
          fminf(fmaxf(1.45f - fabsf(cy - muq[4]), 0.f), 1.f);
      a1 += gq[1] * w;
      w = fminf(fmaxf(1.45f - fabsf(cx - muq[2]), 0.f), 1.f) *
          fminf(fmaxf(1.45f - fabsf(cy - muq[5]), 0.f), 1.f);
      a2 += gq[2] * w;
    }
  }
  const float inv_area = 0.27700831f;  // 1/(4*0.95^2)
  out[(size_t)p * 3 + 0] = a0 * inv_area;
  out[(size_t)p * 3 + 1] = a1 * inv_area;
  out[(size_t)p * 3 + 2] = a2 * inv_area;
}

extern "C" void kernel_launch(void* const* d_in, const int* in_sizes, int n_in,
                              void* d_out, int out_size, void* d_ws, size_t ws_size,
                              hipStream_t stream) {
  const float* x    = (const float*)d_in[0];
  const float* Ks   = (const float*)d_in[1];
  const float* m    = (const float*)d_in[2];
  const float* s    = (const float*)d_in[3];
  const float* h    = (const float*)d_in[4];
  const float* w_c1 = (const float*)d_in[5];
  const int*   c0   = (const int*)d_in[6];
  float* out = (float*)d_out;

  char* ws = (char*)d_ws;
  size_t off = 0;
  float* scales = (float*)(ws + off); off += 1024;                       // 15 floats (padded)
  float2* Ax    = (float2*)(ws + off); off += (size_t)3 * NPIX * 8;      // 6 MB
  float2* Ak    = (float2*)(ws + off); off += (size_t)NKER * NPIX * 8;   // 30 MB
  float*  Gs    = (float*)(ws + off);  off += (size_t)NKER * NPIX * 4;   // 15 MB
  float*  Hs    = (float*)(ws + off);  off += (size_t)3 * NPIX * 4;      // 3 MB
  float*  mu    = (float*)(ws + off);  off += (size_t)6 * NPIX * 4;      // 6 MB

  ksum_kernel<<<NKER, 256, 0, stream>>>(Ks, scales);
  fft_rows_x<<<dim3(512, 3), 64, 0, stream>>>(x, Ax);
  fft_cols_kernel<<<dim3(512, 3), 64, 0, stream>>>(Ax);
  fft_rows_k<<<dim3(512, NKER), 64, 0, stream>>>(Ks, scales, Ak);
  fft_cols_kernel<<<dim3(512, NKER), 64, 0, stream>>>(Ak);
  ifft_cols_mul<<<dim3(512, NKER), 64, 0, stream>>>(Ak, Ax, c0);
  ifft_rows_growth<<<dim3(512, NKER), 64, 0, stream>>>(Ak, m, s, h, Gs);
  combine_hs<<<1024, 256, 0, stream>>>(Gs, w_c1, Hs);
  flow_kernel<<<1024, 256, 0, stream>>>(x, Hs, mu);
  reintegrate_kernel<<<1024, 256, 0, stream>>>(x, mu, out);
}

// Round 2
// 602.781 us; speedup vs baseline: 1.1688x; 1.1688x over previous
//
#include <hip/hip_runtime.h>
#include <math.h>

#define NPIX 262144   // 512*512
#define NKER 15
#define PI_F 3.14159265358979323846f

__device__ __forceinline__ float2 cmul(float2 a, float2 b) {
  return make_float2(a.x * b.x - a.y * b.y, a.x * b.y + a.y * b.x);
}

// twiddle table: tw[u] = e^{-2*pi*i*u/512}, u = 0..255
__device__ __forceinline__ void build_tw(float2* tw, int tid) {
  for (int u = tid; u < 256; u += 64) {
    float s, c;
    sincosf(-2.0f * PI_F * (float)u / 512.0f, &s, &c);
    tw[u] = make_float2(c, s);
  }
}

// Stockham radix-2 DIF, 512 points, 64 threads, ping-pong LDS buffers.
__device__ __forceinline__ float2* fft512(float2* s, float2* d, const float2* tw,
                                          int tid, bool inv) {
#pragma unroll
  for (int stage = 0; stage < 9; ++stage) {
    const int m = 1 << stage;
    __syncthreads();
#pragma unroll
    for (int u = 0; u < 4; ++u) {
      int i = tid + (u << 6);        // 0..255
      int jm = i & ~(m - 1);         // j*m
      float2 c0 = s[i];
      float2 c1 = s[i + 256];
      float2 w = tw[jm];
      float wy = inv ? -w.y : w.y;
      float drx = c0.x - c1.x, dry = c0.y - c1.y;
      d[i + jm] = make_float2(c0.x + c1.x, c0.y + c1.y);
      d[i + jm + m] = make_float2(w.x * drx - wy * dry, w.x * dry + wy * drx);
    }
    float2* t = s; s = d; d = t;
  }
  __syncthreads();
  return s;
}

__global__ void ksum_zero(float* __restrict__ sums) {
  if (threadIdx.x < 16) sums[threadIdx.x] = 0.f;
}

// Per-pixel ownership: thread reads 15 consecutive floats (one pixel, all k),
// k index static -> 15 register accumulators. Wave shuffle-reduce, then one
// global atomicAdd per wave per k.
__global__ void ksum_partial(const float* __restrict__ Ks, float* __restrict__ sums) {
  int tid = blockIdx.x * 256 + threadIdx.x;   // 65536 threads
  float acc[NKER];
#pragma unroll
  for (int k = 0; k < NKER; ++k) acc[k] = 0.f;
  // 4 pixels per thread, contiguous per-thread region => wave reads contiguous 3840B
#pragma unroll
  for (int u = 0; u < 4; ++u) {
    int p = tid + (u << 16);
    const float* src = Ks + (size_t)p * NKER;
#pragma unroll
    for (int k = 0; k < NKER; ++k) acc[k] += src[k];
  }
#pragma unroll
  for (int k = 0; k < NKER; ++k) {
#pragma unroll
    for (int off = 32; off > 0; off >>= 1)
      acc[k] += __shfl_down(acc[k], off, 64);
  }
  if ((threadIdx.x & 63) == 0) {
#pragma unroll
    for (int k = 0; k < NKER; ++k) atomicAdd(&sums[k], acc[k]);
  }
}

// forward row FFT of x channel c  -> Ax[c][row][y]
__global__ void fft_rows_x(const float* __restrict__ x, float2* __restrict__ Ax) {
  __shared__ float2 b0[512], b1[512], tw[256];
  int tid = threadIdx.x, row = blockIdx.x, c = blockIdx.y;
  build_tw(tw, tid);
  for (int u = 0; u < 8; ++u) {
    int y = tid + (u << 6);
    b0[y] = make_float2(x[((size_t)row * 512 + y) * 3 + c], 0.f);
  }
  float2* r = fft512(b0, b1, tw, tid, false);
  float2* dst = Ax + (size_t)c * NPIX + (size_t)row * 512;
  for (int u = 0; u < 8; ++u) { int y = tid + (u << 6); dst[y] = r[y]; }
}

// forward row FFT of fftshift(Ks[:,:,k]) * (1/(sum*N^2)) -> Ak[k][row][y]
__global__ void fft_rows_k(const float* __restrict__ Ks, const float* __restrict__ sums,
                           float2* __restrict__ Ak) {
  __shared__ float2 b0[512], b1[512], tw[256];
  int tid = threadIdx.x, row = blockIdx.x, k = blockIdx.y;
  build_tw(tw, tid);
  float sc = 1.0f / (sums[k] * 262144.0f);   // kernel norm + ifft2 1/N^2
  int rs = (row + 256) & 511;   // 2D fftshift folded into loads
  for (int u = 0; u < 8; ++u) {
    int y = tid + (u << 6);
    int ys = (y + 256) & 511;
    b0[y] = make_float2(Ks[((size_t)rs * 512 + ys) * NKER + k] * sc, 0.f);
  }
  float2* r = fft512(b0, b1, tw, tid, false);
  float2* dst = Ak + (size_t)k * NPIX + (size_t)row * 512;
  for (int u = 0; u < 8; ++u) { int y = tid + (u << 6); dst[y] = r[y]; }
}

// forward column FFT, in place; gridDim.y = #channels
__global__ void fft_cols_kernel(float2* __restrict__ A) {
  __shared__ float2 b0[512], b1[512], tw[256];
  int tid = threadIdx.x, col = blockIdx.x, ch = blockIdx.y;
  build_tw(tw, tid);
  float2* base = A + (size_t)ch * NPIX;
  for (int u = 0; u < 8; ++u) {
    int r = tid + (u << 6);
    b0[r] = base[(size_t)r * 512 + col];
  }
  float2* res = fft512(b0, b1, tw, tid, false);
  for (int u = 0; u < 8; ++u) {
    int r = tid + (u << 6);
    base[(size_t)r * 512 + col] = res[r];
  }
}

// inverse column FFT of (Ak[k] * Ax[c0[k]]), in place into Ak[k]
__global__ void ifft_cols_mul(float2* __restrict__ Ak, const float2* __restrict__ Ax,
                              const int* __restrict__ c0) {
  __shared__ float2 b0[512], b1[512], tw[256];
  int tid = threadIdx.x, col = blockIdx.x, k = blockIdx.y;
  build_tw(tw, tid);
  int c = c0[k];
  float2* bk = Ak + (size_t)k * NPIX;
  const float2* bx = Ax + (size_t)c * NPIX;
  for (int u = 0; u < 8; ++u) {
    int r = tid + (u << 6);
    size_t idx = (size_t)r * 512 + col;
    b0[r] = cmul(bk[idx], bx[idx]);
  }
  float2* res = fft512(b0, b1, tw, tid, true);
  for (int u = 0; u < 8; ++u) {
    int r = tid + (u << 6);
    bk[(size_t)r * 512 + col] = res[r];
  }
}

// inverse row FFT -> Us real -> growth -> Gs[k][row][y]  (Gs includes *h)
__global__ void ifft_rows_growth(const float2* __restrict__ Ak, const float* __restrict__ m,
                                 const float* __restrict__ s, const float* __restrict__ h,
                                 float* __restrict__ Gs) {
  __shared__ float2 b0[512], b1[512], tw[256];
  int tid = threadIdx.x, row = blockIdx.x, k = blockIdx.y;
  build_tw(tw, tid);
  const float2* src = Ak + (size_t)k * NPIX + (size_t)row * 512;
  for (int u = 0; u < 8; ++u) { int y = tid + (u << 6); b0[y] = src[y]; }
  float2* r = fft512(b0, b1, tw, tid, true);
  float mk = m[k], invs = 1.0f / s[k], hk = h[k];
  float* dst = Gs + (size_t)k * NPIX + (size_t)row * 512;
  for (int u = 0; u < 8; ++u) {
    int y = tid + (u << 6);
    float t = (r[y].x - mk) * invs;
    dst[y] = (expf(-0.5f * t * t) * 2.0f - 1.0f) * hk;
  }
}

// Hs[c][p] = sum_k Gs[k][p] * w_c1[k][c]
__global__ void combine_hs(const float* __restrict__ Gs, const float* __restrict__ w,
                           float* __restrict__ Hs) {
  int p = blockIdx.x * 256 + threadIdx.x;
  float a0 = 0.f, a1 = 0.f, a2 = 0.f;
#pragma unroll
  for (int k = 0; k < NKER; ++k) {
    float g = Gs[(size_t)k * NPIX + p];
    a0 += g * w[k * 3 + 0];
    a1 += g * w[k * 3 + 1];
    a2 += g * w[k * 3 + 2];
  }
  Hs[p] = a0; Hs[NPIX + p] = a1; Hs[2 * NPIX + p] = a2;
}

// sobel (zero pad) + alpha + F + mu.  mu layout: mu[p*6 + axis*3 + c]
__global__ void flow_kernel(const float* __restrict__ x, const float* __restrict__ Hs,
                            float* __restrict__ mu) {
  int p = blockIdx.x * 256 + threadIdx.x;
  int px = p >> 9, py = p & 511;
  float syH0 = 0.f, syH1 = 0.f, syH2 = 0.f;
  float sxH0 = 0.f, sxH1 = 0.f, sxH2 = 0.f;
  float syX = 0.f, sxX = 0.f;
#pragma unroll
  for (int di = -1; di <= 1; ++di) {
#pragma unroll
    for (int dj = -1; dj <= 1; ++dj) {
      if (di == 0 && dj == 0) continue;
      int xi = px + di, yj = py + dj;
      if ((unsigned)xi >= 512u || (unsigned)yj >= 512u) continue;  // zero pad
      float wy = (float)di * ((dj == 0) ? 2.f : 1.f);  // d/dx coeff
      float wx = (float)dj * ((di == 0) ? 2.f : 1.f);  // d/dy coeff
      int q = (xi << 9) | yj;
      float h0 = Hs[q], h1 = Hs[NPIX + q], h2 = Hs[2 * NPIX + q];
      syH0 += wy * h0; syH1 += wy * h1; syH2 += wy * h2;
      sxH0 += wx * h0; sxH1 += wx * h1; sxH2 += wx * h2;
      float xs = x[(size_t)q * 3 + 0] + x[(size_t)q * 3 + 1] + x[(size_t)q * 3 + 2];
      syX += wy * xs; sxX += wx * xs;
    }
  }
  float cxp = (float)px + 0.5f, cyp = (float)py + 0.5f;
  float* mup = mu + (size_t)p * 6;
  float syH[3] = {syH0, syH1, syH2};
  float sxH[3] = {sxH0, sxH1, sxH2};
#pragma unroll
  for (int c = 0; c < 3; ++c) {
    float xc = x[(size_t)p * 3 + c];
    float t = xc * 0.5f;                 // x / THETA_X
    float alpha = fminf(t * t, 1.0f);    // clip((x/2)^2, 0, 1)
    float F0 = syH[c] * (1.f - alpha) - syX * alpha;
    float F1 = sxH[c] * (1.f - alpha) - sxX * alpha;
    float m0 = cxp + fminf(fmaxf(0.2f * F0, -1.05f), 1.05f);
    float m1 = cyp + fminf(fmaxf(0.2f * F1, -1.05f), 1.05f);
    mup[c]     = fminf(fmaxf(m0, 0.95f), 511.05f);
    mup[3 + c] = fminf(fmaxf(m1, 0.95f), 511.05f);
  }
}

// 25-offset reintegration gather
__global__ void reintegrate_kernel(const float* __restrict__ x, const float* __restrict__ mu,
                                   float* __restrict__ out) {
  int p = blockIdx.x * 256 + threadIdx.x;
  int px = p >> 9, py = p & 511;
  float cx = (float)px + 0.5f, cy = (float)py + 0.5f;
  float a0 = 0.f, a1 = 0.f, a2 = 0.f;
#pragma unroll
  for (int dx = -2; dx <= 2; ++dx) {
    int qx = (px - dx + 512) & 511;
#pragma unroll
    for (int dy = -2; dy <= 2; ++dy) {
      int qy = (py - dy + 512) & 511;
      int q = (qx << 9) | qy;
      const float* muq = mu + (size_t)q * 6;
      const float* gq = x + (size_t)q * 3;
      float w;
      w = fminf(fmaxf(1.45f - fabsf(cx - muq[0]), 0.f), 1.f) *
          fminf(fmaxf(1.45f - fabsf(cy - muq[3]), 0.f), 1.f);
      a0 += gq[0] * w;
      w = fminf(fmaxf(1.45f - fabsf(cx - muq[1]), 0.f), 1.f) *
          fminf(fmaxf(1.45f - fabsf(cy - muq[4]), 0.f), 1.f);
      a1 += gq[1] * w;
      w = fminf(fmaxf(1.45f - fabsf(cx - muq[2]), 0.f), 1.f) *
          fminf(fmaxf(1.45f - fabsf(cy - muq[5]), 0.f), 1.f);
      a2 += gq[2] * w;
    }
  }
  const float inv_area = 0.27700831f;  // 1/(4*0.95^2)
  out[(size_t)p * 3 + 0] = a0 * inv_area;
  out[(size_t)p * 3 + 1] = a1 * inv_area;
  out[(size_t)p * 3 + 2] = a2 * inv_area;
}

extern "C" void kernel_launch(void* const* d_in, const int* in_sizes, int n_in,
                              void* d_out, int out_size, void* d_ws, size_t ws_size,
                              hipStream_t stream) {
  const float* x    = (const float*)d_in[0];
  const float* Ks   = (const float*)d_in[1];
  const float* m    = (const float*)d_in[2];
  const float* s    = (const float*)d_in[3];
  const float* h    = (const float*)d_in[4];
  const float* w_c1 = (const float*)d_in[5];
  const int*   c0   = (const int*)d_in[6];
  float* out = (float*)d_out;

  char* ws = (char*)d_ws;
  size_t off = 0;
  float* sums  = (float*)(ws + off); off += 1024;                        // 15 floats (padded)
  float2* Ax   = (float2*)(ws + off); off += (size_t)3 * NPIX * 8;       // 6 MB
  float2* Ak   = (float2*)(ws + off); off += (size_t)NKER * NPIX * 8;    // 30 MB
  float*  Gs   = (float*)(ws + off);  off += (size_t)NKER * NPIX * 4;    // 15 MB
  float*  Hs   = (float*)(ws + off);  off += (size_t)3 * NPIX * 4;       // 3 MB
  float*  mu   = (float*)(ws + off);  off += (size_t)6 * NPIX * 4;       // 6 MB

  ksum_zero<<<1, 64, 0, stream>>>(sums);
  ksum_partial<<<256, 256, 0, stream>>>(Ks, sums);
  fft_rows_x<<<dim3(512, 3), 64, 0, stream>>>(x, Ax);
  fft_cols_kernel<<<dim3(512, 3), 64, 0, stream>>>(Ax);
  fft_rows_k<<<dim3(512, NKER), 64, 0, stream>>>(Ks, sums, Ak);
  fft_cols_kernel<<<dim3(512, NKER), 64, 0, stream>>>(Ak);
  ifft_cols_mul<<<dim3(512, NKER), 64, 0, stream>>>(Ak, Ax, c0);
  ifft_rows_growth<<<dim3(512, NKER), 64, 0, stream>>>(Ak, m, s, h, Gs);
  combine_hs<<<1024, 256, 0, stream>>>(Gs, w_c1, Hs);
  flow_kernel<<<1024, 256, 0, stream>>>(x, Hs, mu);
  reintegrate_kernel<<<1024, 256, 0, stream>>>(x, mu, out);
}

// Round 3
// 236.803 us; speedup vs baseline: 2.9752x; 2.5455x over previous
//
#include <hip/hip_runtime.h>
#include <math.h>

#define NPIX 262144   // 512*512
#define NKER 15
#define PI_F 3.14159265358979323846f
#define CPAD 516      // 512 + 4 float2 pad -> 8-bank skew per column (2-way only)

__device__ __forceinline__ float2 cmul(float2 a, float2 b) {
  return make_float2(a.x * b.x - a.y * b.y, a.x * b.y + a.y * b.x);
}

// twiddle table: tw[u] = e^{-2*pi*i*u/512}, u = 0..255
__device__ __forceinline__ void build_tw(float2* tw, int tid, int nthr) {
  for (int u = tid; u < 256; u += nthr) {
    float s, c;
    sincosf(-2.0f * PI_F * (float)u / 512.0f, &s, &c);
    tw[u] = make_float2(c, s);
  }
}

// Stockham radix-2 DIF, 512 points, 64 lanes per transform, ping-pong buffers.
// All threads of the block must call this (uniform __syncthreads).
__device__ __forceinline__ float2* fft512(float2* s, float2* d, const float2* tw,
                                          int tid, bool inv) {
#pragma unroll
  for (int stage = 0; stage < 9; ++stage) {
    const int m = 1 << stage;
    __syncthreads();
#pragma unroll
    for (int u = 0; u < 4; ++u) {
      int i = tid + (u << 6);        // 0..255
      int jm = i & ~(m - 1);         // j*m
      float2 c0 = s[i];
      float2 c1 = s[i + 256];
      float2 w = tw[jm];
      float wy = inv ? -w.y : w.y;
      float drx = c0.x - c1.x, dry = c0.y - c1.y;
      d[i + jm] = make_float2(c0.x + c1.x, c0.y + c1.y);
      d[i + jm + m] = make_float2(w.x * drx - wy * dry, w.x * dry + wy * drx);
    }
    float2* t = s; s = d; d = t;
  }
  __syncthreads();
  return s;
}

// ---- ksum stage 1: block-level reduction, no global atomics ----
// 1024 blocks x 256 threads, 1 pixel/thread -> partial[block*16 + k]
__global__ void ksum_partial(const float* __restrict__ Ks, float* __restrict__ partial) {
  __shared__ float wsum[4][16];
  int p = blockIdx.x * 256 + threadIdx.x;
  const float* src = Ks + (size_t)p * NKER;
  float acc[NKER];
#pragma unroll
  for (int k = 0; k < NKER; ++k) acc[k] = src[k];
#pragma unroll
  for (int k = 0; k < NKER; ++k) {
#pragma unroll
    for (int off = 32; off > 0; off >>= 1)
      acc[k] += __shfl_down(acc[k], off, 64);
  }
  int wave = threadIdx.x >> 6;
  if ((threadIdx.x & 63) == 0) {
#pragma unroll
    for (int k = 0; k < NKER; ++k) wsum[wave][k] = acc[k];
  }
  __syncthreads();
  if (threadIdx.x < NKER) {
    int k = threadIdx.x;
    partial[blockIdx.x * 16 + k] = wsum[0][k] + wsum[1][k] + wsum[2][k] + wsum[3][k];
  }
}

// ---- ksum stage 2: single block reduces 1024 partials ----
__global__ void ksum_final(const float* __restrict__ partial, float* __restrict__ sums) {
  __shared__ float red[256];
  int t = threadIdx.x;
  int k = t & 15, g = t >> 4;          // 16 groups x 16 k-slots
  float acc = 0.f;
  for (int b = g; b < 1024; b += 16) acc += partial[b * 16 + k];
  red[t] = acc;
  __syncthreads();
  if (t < 16) {
    float s = 0.f;
#pragma unroll
    for (int g2 = 0; g2 < 16; ++g2) s += red[g2 * 16 + t];
    sums[t] = s;
  }
}

// forward row FFT of x channel c  -> Ax[c][row][y]
__global__ void fft_rows_x(const float* __restrict__ x, float2* __restrict__ Ax) {
  __shared__ float2 b0[512], b1[512], tw[256];
  int tid = threadIdx.x, row = blockIdx.x, c = blockIdx.y;
  build_tw(tw, tid, 64);
  for (int u = 0; u < 8; ++u) {
    int y = tid + (u << 6);
    b0[y] = make_float2(x[((size_t)row * 512 + y) * 3 + c], 0.f);
  }
  float2* r = fft512(b0, b1, tw, tid, false);
  float2* dst = Ax + (size_t)c * NPIX + (size_t)row * 512;
  for (int u = 0; u < 8; ++u) { int y = tid + (u << 6); dst[y] = r[y]; }
}

// forward row FFT of fftshift(Ks[:,:,k]) * (1/(sum*N^2)) -> Ak[k][row][y]
__global__ void fft_rows_k(const float* __restrict__ Ks, const float* __restrict__ sums,
                           float2* __restrict__ Ak) {
  __shared__ float2 b0[512], b1[512], tw[256];
  int tid = threadIdx.x, row = blockIdx.x, k = blockIdx.y;
  build_tw(tw, tid, 64);
  float sc = 1.0f / (sums[k] * 262144.0f);   // kernel norm + ifft2 1/N^2
  int rs = (row + 256) & 511;   // 2D fftshift folded into loads
  for (int u = 0; u < 8; ++u) {
    int y = tid + (u << 6);
    int ys = (y + 256) & 511;
    b0[y] = make_float2(Ks[((size_t)rs * 512 + ys) * NKER + k] * sc, 0.f);
  }
  float2* r = fft512(b0, b1, tw, tid, false);
  float2* dst = Ak + (size_t)k * NPIX + (size_t)row * 512;
  for (int u = 0; u < 8; ++u) { int y = tid + (u << 6); dst[y] = r[y]; }
}

// ---- slab column FFT: 512 threads, 8 adjacent columns, coalesced global ----
__global__ void fft_cols_slab(float2* __restrict__ A) {
  __shared__ float2 buf0[8][CPAD], buf1[8][CPAD], tw[256];
  int t = threadIdx.x, col0 = blockIdx.x * 8, ch = blockIdx.y;
  build_tw(tw, t, 512);
  float2* base = A + (size_t)ch * NPIX;
  // coalesced load: 8 consecutive lanes -> 8 consecutive columns of one row
#pragma unroll
  for (int u = 0; u < 8; ++u) {
    int idx = (u << 9) + t;
    int row = idx >> 3, c = idx & 7;
    buf0[c][row] = base[(size_t)row * 512 + col0 + c];
  }
  int cc = t >> 6, lane = t & 63;
  float2* res = fft512(&buf0[cc][0], &buf1[cc][0], tw, lane, false);
  // res parity identical across columns (9 stages); store coalesced
  int parity_src_is_b1 = (res == &buf1[cc][0]);
#pragma unroll
  for (int u = 0; u < 8; ++u) {
    int idx = (u << 9) + t;
    int row = idx >> 3, c = idx & 7;
    float2 v = parity_src_is_b1 ? buf1[c][row] : buf0[c][row];
    base[(size_t)row * 512 + col0 + c] = v;
  }
}

// ---- slab inverse column FFT of (Ak[k]*Ax[c0[k]]), in place into Ak[k] ----
__global__ void ifft_cols_mul_slab(float2* __restrict__ Ak, const float2* __restrict__ Ax,
                                   const int* __restrict__ c0) {
  __shared__ float2 buf0[8][CPAD], buf1[8][CPAD], tw[256];
  int t = threadIdx.x, col0 = blockIdx.x * 8, k = blockIdx.y;
  build_tw(tw, t, 512);
  int c0k = c0[k];
  float2* bk = Ak + (size_t)k * NPIX;
  const float2* bx = Ax + (size_t)c0k * NPIX;
#pragma unroll
  for (int u = 0; u < 8; ++u) {
    int idx = (u << 9) + t;
    int row = idx >> 3, c = idx & 7;
    size_t g = (size_t)row * 512 + col0 + c;
    buf0[c][row] = cmul(bk[g], bx[g]);
  }
  int cc = t >> 6, lane = t & 63;
  float2* res = fft512(&buf0[cc][0], &buf1[cc][0], tw, lane, true);
  int parity_src_is_b1 = (res == &buf1[cc][0]);
#pragma unroll
  for (int u = 0; u < 8; ++u) {
    int idx = (u << 9) + t;
    int row = idx >> 3, c = idx & 7;
    float2 v = parity_src_is_b1 ? buf1[c][row] : buf0[c][row];
    bk[(size_t)row * 512 + col0 + c] = v;
  }
}

// inverse row FFT -> Us real -> growth -> Gs[k][row][y]  (Gs includes *h)
__global__ void ifft_rows_growth(const float2* __restrict__ Ak, const float* __restrict__ m,
                                 const float* __restrict__ s, const float* __restrict__ h,
                                 float* __restrict__ Gs) {
  __shared__ float2 b0[512], b1[512], tw[256];
  int tid = threadIdx.x, row = blockIdx.x, k = blockIdx.y;
  build_tw(tw, tid, 64);
  const float2* src = Ak + (size_t)k * NPIX + (size_t)row * 512;
  for (int u = 0; u < 8; ++u) { int y = tid + (u << 6); b0[y] = src[y]; }
  float2* r = fft512(b0, b1, tw, tid, true);
  float mk = m[k], invs = 1.0f / s[k], hk = h[k];
  float* dst = Gs + (size_t)k * NPIX + (size_t)row * 512;
  for (int u = 0; u < 8; ++u) {
    int y = tid + (u << 6);
    float t = (r[y].x - mk) * invs;
    dst[y] = (expf(-0.5f * t * t) * 2.0f - 1.0f) * hk;
  }
}

// Hs[c][p] = sum_k Gs[k][p] * w_c1[k][c]
__global__ void combine_hs(const float* __restrict__ Gs, const float* __restrict__ w,
                           float* __restrict__ Hs) {
  int p = blockIdx.x * 256 + threadIdx.x;
  float a0 = 0.f, a1 = 0.f, a2 = 0.f;
#pragma unroll
  for (int k = 0; k < NKER; ++k) {
    float g = Gs[(size_t)k * NPIX + p];
    a0 += g * w[k * 3 + 0];
    a1 += g * w[k * 3 + 1];
    a2 += g * w[k * 3 + 2];
  }
  Hs[p] = a0; Hs[NPIX + p] = a1; Hs[2 * NPIX + p] = a2;
}

// sobel (zero pad) + alpha + F + mu.  mu layout: mu[p*6 + axis*3 + c]
__global__ void flow_kernel(const float* __restrict__ x, const float* __restrict__ Hs,
                            float* __restrict__ mu) {
  int p = blockIdx.x * 256 + threadIdx.x;
  int px = p >> 9, py = p & 511;
  float syH0 = 0.f, syH1 = 0.f, syH2 = 0.f;
  float sxH0 = 0.f, sxH1 = 0.f, sxH2 = 0.f;
  float syX = 0.f, sxX = 0.f;
#pragma unroll
  for (int di = -1; di <= 1; ++di) {
#pragma unroll
    for (int dj = -1; dj <= 1; ++dj) {
      if (di == 0 && dj == 0) continue;
      int xi = px + di, yj = py + dj;
      if ((unsigned)xi >= 512u || (unsigned)yj >= 512u) continue;  // zero pad
      float wy = (float)di * ((dj == 0) ? 2.f : 1.f);  // d/dx coeff
      float wx = (float)dj * ((di == 0) ? 2.f : 1.f);  // d/dy coeff
      int q = (xi << 9) | yj;
      float h0 = Hs[q], h1 = Hs[NPIX + q], h2 = Hs[2 * NPIX + q];
      syH0 += wy * h0; syH1 += wy * h1; syH2 += wy * h2;
      sxH0 += wx * h0; sxH1 += wx * h1; sxH2 += wx * h2;
      float xs = x[(size_t)q * 3 + 0] + x[(size_t)q * 3 + 1] + x[(size_t)q * 3 + 2];
      syX += wy * xs; sxX += wx * xs;
    }
  }
  float cxp = (float)px + 0.5f, cyp = (float)py + 0.5f;
  float* mup = mu + (size_t)p * 6;
  float syH[3] = {syH0, syH1, syH2};
  float sxH[3] = {sxH0, sxH1, sxH2};
#pragma unroll
  for (int c = 0; c < 3; ++c) {
    float xc = x[(size_t)p * 3 + c];
    float t = xc * 0.5f;                 // x / THETA_X
    float alpha = fminf(t * t, 1.0f);    // clip((x/2)^2, 0, 1)
    float F0 = syH[c] * (1.f - alpha) - syX * alpha;
    float F1 = sxH[c] * (1.f - alpha) - sxX * alpha;
    float m0 = cxp + fminf(fmaxf(0.2f * F0, -1.05f), 1.05f);
    float m1 = cyp + fminf(fmaxf(0.2f * F1, -1.05f), 1.05f);
    mup[c]     = fminf(fmaxf(m0, 0.95f), 511.05f);
    mup[3 + c] = fminf(fmaxf(m1, 0.95f), 511.05f);
  }
}

// 25-offset reintegration gather
__global__ void reintegrate_kernel(const float* __restrict__ x, const float* __restrict__ mu,
                                   float* __restrict__ out) {
  int p = blockIdx.x * 256 + threadIdx.x;
  int px = p >> 9, py = p & 511;
  float cx = (float)px + 0.5f, cy = (float)py + 0.5f;
  float a0 = 0.f, a1 = 0.f, a2 = 0.f;
#pragma unroll
  for (int dx = -2; dx <= 2; ++dx) {
    int qx = (px - dx + 512) & 511;
#pragma unroll
    for (int dy = -2; dy <= 2; ++dy) {
      int qy = (py - dy + 512) & 511;
      int q = (qx << 9) | qy;
      const float* muq = mu + (size_t)q * 6;
      const float* gq = x + (size_t)q * 3;
      float w;
      w = fminf(fmaxf(1.45f - fabsf(cx - muq[0]), 0.f), 1.f) *
          fminf(fmaxf(1.45f - fabsf(cy - muq[3]), 0.f), 1.f);
      a0 += gq[0] * w;
      w = fminf(fmaxf(1.45f - fabsf(cx - muq[1]), 0.f), 1.f) *
          fminf(fmaxf(1.45f - fabsf(cy - muq[4]), 0.f), 1.f);
      a1 += gq[1] * w;
      w = fminf(fmaxf(1.45f - fabsf(cx - muq[2]), 0.f), 1.f) *
          fminf(fmaxf(1.45f - fabsf(cy - muq[5]), 0.f), 1.f);
      a2 += gq[2] * w;
    }
  }
  const float inv_area = 0.27700831f;  // 1/(4*0.95^2)
  out[(size_t)p * 3 + 0] = a0 * inv_area;
  out[(size_t)p * 3 + 1] = a1 * inv_area;
  out[(size_t)p * 3 + 2] = a2 * inv_area;
}

extern "C" void kernel_launch(void* const* d_in, const int* in_sizes, int n_in,
                              void* d_out, int out_size, void* d_ws, size_t ws_size,
                              hipStream_t stream) {
  const float* x    = (const float*)d_in[0];
  const float* Ks   = (const float*)d_in[1];
  const float* m    = (const float*)d_in[2];
  const float* s    = (const float*)d_in[3];
  const float* h    = (const float*)d_in[4];
  const float* w_c1 = (const float*)d_in[5];
  const int*   c0   = (const int*)d_in[6];
  float* out = (float*)d_out;

  char* ws = (char*)d_ws;
  size_t off = 0;
  float* sums    = (float*)(ws + off); off += 1024;                      // 16 floats (padded)
  float* partial = (float*)(ws + off); off += 1024 * 16 * 4;             // 64 KB
  float2* Ax   = (float2*)(ws + off); off += (size_t)3 * NPIX * 8;       // 6 MB
  float2* Ak   = (float2*)(ws + off); off += (size_t)NKER * NPIX * 8;    // 30 MB
  float*  Gs   = (float*)(ws + off);  off += (size_t)NKER * NPIX * 4;    // 15 MB
  float*  Hs   = (float*)(ws + off);  off += (size_t)3 * NPIX * 4;       // 3 MB
  float*  mu   = (float*)(ws + off);  off += (size_t)6 * NPIX * 4;       // 6 MB

  ksum_partial<<<1024, 256, 0, stream>>>(Ks, partial);
  ksum_final<<<1, 256, 0, stream>>>(partial, sums);
  fft_rows_x<<<dim3(512, 3), 64, 0, stream>>>(x, Ax);
  fft_cols_slab<<<dim3(64, 3), 512, 0, stream>>>(Ax);
  fft_rows_k<<<dim3(512, NKER), 64, 0, stream>>>(Ks, sums, Ak);
  fft_cols_slab<<<dim3(64, NKER), 512, 0, stream>>>(Ak);
  ifft_cols_mul_slab<<<dim3(64, NKER), 512, 0, stream>>>(Ak, Ax, c0);
  ifft_rows_growth<<<dim3(512, NKER), 64, 0, stream>>>(Ak, m, s, h, Gs);
  combine_hs<<<1024, 256, 0, stream>>>(Gs, w_c1, Hs);
  flow_kernel<<<1024, 256, 0, stream>>>(x, Hs, mu);
  reintegrate_kernel<<<1024, 256, 0, stream>>>(x, mu, out);
}

// Round 4
// 181.172 us; speedup vs baseline: 3.8888x; 1.3071x over previous
//
#include <hip/hip_runtime.h>
#include <math.h>

#define NPIX 262144   // 512*512
#define NKER 15
#define PI_F 3.14159265358979323846f
#define CPAD 516      // slab column chunk stride (float2 elems), bank skew

__device__ __forceinline__ float2 cadd(float2 a, float2 b) { return make_float2(a.x + b.x, a.y + b.y); }
__device__ __forceinline__ float2 csub(float2 a, float2 b) { return make_float2(a.x - b.x, a.y - b.y); }
__device__ __forceinline__ float2 cmul(float2 a, float2 b) {
  return make_float2(a.x * b.x - a.y * b.y, a.x * b.y + a.y * b.x);
}

// tw[u] = e^{-2*pi*i*u/512}, u = 0..511
__device__ __forceinline__ void build_tw512(float2* tw, int tid, int nthr) {
  for (int u = tid; u < 512; u += nthr) {
    float s, c;
    sincosf(-2.0f * PI_F * (float)u / 512.0f, &s, &c);
    tw[u] = make_float2(c, s);
  }
}

template <bool INV>
__device__ __forceinline__ float2 twmul(float2 a, float2 w) {
  float wy = INV ? -w.y : w.y;
  return make_float2(a.x * w.x - a.y * wy, a.x * wy + a.y * w.x);
}

// 8-point DIF DFT in registers, natural-order outputs. INV => conjugate.
template <bool INV>
__device__ __forceinline__ void dft8(float2 a[8]) {
  const float R = 0.70710678118654752f;
  float2 t0 = cadd(a[0], a[4]), u0 = csub(a[0], a[4]);
  float2 t1 = cadd(a[1], a[5]), u1 = csub(a[1], a[5]);
  float2 t2 = cadd(a[2], a[6]), u2 = csub(a[2], a[6]);
  float2 t3 = cadd(a[3], a[7]), u3 = csub(a[3], a[7]);
  // u1 *= W8^{±1}, u2 *= ∓i, u3 *= W8^{±3}
  u1 = INV ? make_float2(R * (u1.x - u1.y), R * (u1.x + u1.y))
           : make_float2(R * (u1.x + u1.y), R * (u1.y - u1.x));
  u2 = INV ? make_float2(-u2.y, u2.x) : make_float2(u2.y, -u2.x);
  u3 = INV ? make_float2(-R * (u3.x + u3.y), R * (u3.x - u3.y))
           : make_float2(R * (u3.y - u3.x), -R * (u3.x + u3.y));
  float2 e0 = cadd(t0, t2), f0 = csub(t0, t2);
  float2 e1 = cadd(t1, t3), f1 = csub(t1, t3);
  f1 = INV ? make_float2(-f1.y, f1.x) : make_float2(f1.y, -f1.x);
  float2 g0 = cadd(u0, u2), h0 = csub(u0, u2);
  float2 g1 = cadd(u1, u3), h1 = csub(u1, u3);
  h1 = INV ? make_float2(-h1.y, h1.x) : make_float2(h1.y, -h1.x);
  a[0] = cadd(e0, e1); a[4] = csub(e0, e1);
  a[2] = cadd(f0, f1); a[6] = csub(f0, f1);
  a[1] = cadd(g0, g1); a[5] = csub(g0, g1);
  a[3] = cadd(h0, h1); a[7] = csub(h0, h1);
}

// 512-pt Stockham radix-8, 3 stages, one wave, 8 pts/thread.
// Input: a[q] = point at natural index (lane + 64q). Output: same positions.
// buf = wave-private 512-float2 scratch. No barriers (in-order DS pipe per wave).
template <bool INV>
__device__ __forceinline__ void fft512_r8(float2 a[8], float2* buf,
                                          const float2* tw, int lane) {
  // stage m=1: h = lane, out[8*lane + q]
  dft8<INV>(a);
#pragma unroll
  for (int q = 1; q < 8; ++q) a[q] = twmul<INV>(a[q], tw[(lane * q) & 511]);
#pragma unroll
  for (int q = 0; q < 8; ++q) buf[8 * lane + q] = a[q];
  // stage m=8: read s[lane + 64q], h = (lane/8)*8, out[8h + 8q + (lane-h)]
#pragma unroll
  for (int q = 0; q < 8; ++q) a[q] = buf[lane + 64 * q];
  dft8<INV>(a);
  int h = lane & ~7;
#pragma unroll
  for (int q = 1; q < 8; ++q) a[q] = twmul<INV>(a[q], tw[(h * q) & 511]);
#pragma unroll
  for (int q = 0; q < 8; ++q) buf[8 * h + 8 * q + (lane - h)] = a[q];
  // stage m=64: h = 0, no twiddle; result stays in regs at natural positions
#pragma unroll
  for (int q = 0; q < 8; ++q) a[q] = buf[lane + 64 * q];
  dft8<INV>(a);
}

// ---- ksum: block reduction (no global atomics) ----
__global__ void ksum_partial(const float* __restrict__ Ks, float* __restrict__ partial) {
  __shared__ float wsum[4][16];
  int p = blockIdx.x * 256 + threadIdx.x;
  const float* src = Ks + (size_t)p * NKER;
  float acc[NKER];
#pragma unroll
  for (int k = 0; k < NKER; ++k) acc[k] = src[k];
#pragma unroll
  for (int k = 0; k < NKER; ++k) {
#pragma unroll
    for (int off = 32; off > 0; off >>= 1) acc[k] += __shfl_down(acc[k], off, 64);
  }
  int wave = threadIdx.x >> 6;
  if ((threadIdx.x & 63) == 0) {
#pragma unroll
    for (int k = 0; k < NKER; ++k) wsum[wave][k] = acc[k];
  }
  __syncthreads();
  if (threadIdx.x < NKER) {
    int k = threadIdx.x;
    partial[blockIdx.x * 16 + k] = wsum[0][k] + wsum[1][k] + wsum[2][k] + wsum[3][k];
  }
}

__global__ void ksum_final(const float* __restrict__ partial, float* __restrict__ sums) {
  __shared__ float red[256];
  int t = threadIdx.x;
  int k = t & 15, g = t >> 4;
  float acc = 0.f;
  for (int b = g; b < 1024; b += 16) acc += partial[b * 16 + k];
  red[t] = acc;
  __syncthreads();
  if (t < 16) {
    float s = 0.f;
#pragma unroll
    for (int g2 = 0; g2 < 16; ++g2) s += red[g2 * 16 + t];
    sums[t] = s;
  }
}

// ---- row FFT of x: 4 waves/block, wave per row -> Ax[c][row][y] ----
__global__ void fft_rows_x(const float* __restrict__ x, float2* __restrict__ Ax) {
  __shared__ float2 sbuf[4][512];
  __shared__ float2 tw[512];
  int t = threadIdx.x, wave = t >> 6, lane = t & 63;
  int row = blockIdx.x * 4 + wave, c = blockIdx.y;
  build_tw512(tw, t, 256);
  __syncthreads();
  float2 a[8];
#pragma unroll
  for (int q = 0; q < 8; ++q)
    a[q] = make_float2(x[((size_t)row * 512 + lane + 64 * q) * 3 + c], 0.f);
  fft512_r8<false>(a, &sbuf[wave][0], tw, lane);
  float2* dst = Ax + (size_t)c * NPIX + (size_t)row * 512;
#pragma unroll
  for (int q = 0; q < 8; ++q) dst[lane + 64 * q] = a[q];
}

// ---- row FFT of fftshift(Ks[:,:,k]) * 1/(sum*N^2) -> Ak[k][row][y] ----
__global__ void fft_rows_k(const float* __restrict__ Ks, const float* __restrict__ sums,
                           float2* __restrict__ Ak) {
  __shared__ float2 sbuf[4][512];
  __shared__ float2 tw[512];
  int t = threadIdx.x, wave = t >> 6, lane = t & 63;
  int row = blockIdx.x * 4 + wave, k = blockIdx.y;
  build_tw512(tw, t, 256);
  __syncthreads();
  float sc = 1.0f / (sums[k] * 262144.0f);
  int rs = (row + 256) & 511;
  float2 a[8];
#pragma unroll
  for (int q = 0; q < 8; ++q) {
    int ys = (lane + 64 * q + 256) & 511;
    a[q] = make_float2(Ks[((size_t)rs * 512 + ys) * NKER + k] * sc, 0.f);
  }
  fft512_r8<false>(a, &sbuf[wave][0], tw, lane);
  float2* dst = Ak + (size_t)k * NPIX + (size_t)row * 512;
#pragma unroll
  for (int q = 0; q < 8; ++q) dst[lane + 64 * q] = a[q];
}

// ---- fused column pass: colFFT(Ax[c0k]) (regs) , colFFT(Ak) , cmul , icolFFT ----
// 512 threads = 8 waves, wave per column; 8 adjacent columns per block.
__global__ void fused_cols(float2* __restrict__ Ak, const float2* __restrict__ Ax,
                           const int* __restrict__ c0) {
  __shared__ float2 buf[8 * CPAD];
  __shared__ float2 tw[512];
  int t = threadIdx.x, col0 = blockIdx.x * 8, k = blockIdx.y;
  int c = t >> 6, lane = t & 63;
  build_tw512(tw, t, 512);
  int c0k = c0[k];
  const float2* bx = Ax + (size_t)c0k * NPIX;
  float2* bk = Ak + (size_t)k * NPIX;
  // stage Ax slab (coalesced)
#pragma unroll
  for (int u = 0; u < 8; ++u) {
    int idx = (u << 9) + t;
    int row = idx >> 3, cc = idx & 7;
    buf[cc * CPAD + row] = bx[(size_t)row * 512 + col0 + cc];
  }
  __syncthreads();
  // forward column FFT of Ax -> X̂ kept in regs
  float2 xh[8];
#pragma unroll
  for (int q = 0; q < 8; ++q) xh[q] = buf[c * CPAD + lane + 64 * q];
  fft512_r8<false>(xh, &buf[c * CPAD], tw, lane);
  __syncthreads();
  // stage Ak slab (coalesced)
#pragma unroll
  for (int u = 0; u < 8; ++u) {
    int idx = (u << 9) + t;
    int row = idx >> 3, cc = idx & 7;
    buf[cc * CPAD + row] = bk[(size_t)row * 512 + col0 + cc];
  }
  __syncthreads();
  // forward column FFT of Ak, multiply, inverse column FFT
  float2 a[8];
#pragma unroll
  for (int q = 0; q < 8; ++q) a[q] = buf[c * CPAD + lane + 64 * q];
  fft512_r8<false>(a, &buf[c * CPAD], tw, lane);
#pragma unroll
  for (int q = 0; q < 8; ++q) a[q] = cmul(a[q], xh[q]);
  fft512_r8<true>(a, &buf[c * CPAD], tw, lane);
#pragma unroll
  for (int q = 0; q < 8; ++q) buf[c * CPAD + lane + 64 * q] = a[q];
  __syncthreads();
  // coalesced store back to Ak
#pragma unroll
  for (int u = 0; u < 8; ++u) {
    int idx = (u << 9) + t;
    int row = idx >> 3, cc = idx & 7;
    bk[(size_t)row * 512 + col0 + cc] = buf[cc * CPAD + row];
  }
}

// ---- fused inverse row FFT + growth + w_c1 combine -> Hs[c][p] ----
// 1 block per row, 4 waves split the 15 kernels {0-3}{4-7}{8-11}{12-14}.
__global__ void irows_growth_combine(const float2* __restrict__ Ak,
                                     const float* __restrict__ m, const float* __restrict__ s,
                                     const float* __restrict__ h, const float* __restrict__ w,
                                     float* __restrict__ Hs) {
  __shared__ float2 sbuf[4][512];
  __shared__ float2 tw[512];
  __shared__ float accL[4][3][512];
  __shared__ float mk[16], isk[16], hk[16], wk[16][3];
  int t = threadIdx.x, wave = t >> 6, lane = t & 63;
  int row = blockIdx.x;
  build_tw512(tw, t, 256);
  if (t < NKER) {
    mk[t] = m[t]; isk[t] = 1.0f / s[t]; hk[t] = h[t];
    wk[t][0] = w[t * 3 + 0]; wk[t][1] = w[t * 3 + 1]; wk[t][2] = w[t * 3 + 2];
  }
  __syncthreads();
  float acc[3][8];
#pragma unroll
  for (int cc = 0; cc < 3; ++cc)
#pragma unroll
    for (int q = 0; q < 8; ++q) acc[cc][q] = 0.f;
  int kbeg = wave * 4, kend = (wave == 3) ? 15 : kbeg + 4;
  for (int k = kbeg; k < kend; ++k) {
    const float2* src = Ak + (size_t)k * NPIX + (size_t)row * 512;
    float2 a[8];
#pragma unroll
    for (int q = 0; q < 8; ++q) a[q] = src[lane + 64 * q];
    fft512_r8<true>(a, &sbuf[wave][0], tw, lane);
    float mm = mk[k], is = isk[k], hh = hk[k];
    float w0 = wk[k][0], w1 = wk[k][1], w2 = wk[k][2];
#pragma unroll
    for (int q = 0; q < 8; ++q) {
      float tt = (a[q].x - mm) * is;
      float g = (expf(-0.5f * tt * tt) * 2.0f - 1.0f) * hh;
      acc[0][q] += g * w0; acc[1][q] += g * w1; acc[2][q] += g * w2;
    }
  }
#pragma unroll
  for (int cc = 0; cc < 3; ++cc)
#pragma unroll
    for (int q = 0; q < 8; ++q) accL[wave][cc][lane + 64 * q] = acc[cc][q];
  __syncthreads();
  // final reduce: thread t handles positions t and t+256 for each channel
#pragma unroll
  for (int cc = 0; cc < 3; ++cc) {
#pragma unroll
    for (int rep = 0; rep < 2; ++rep) {
      int p = t + (rep << 8);
      float v = accL[0][cc][p] + accL[1][cc][p] + accL[2][cc][p] + accL[3][cc][p];
      Hs[(size_t)cc * NPIX + (size_t)row * 512 + p] = v;
    }
  }
}

// sobel (zero pad) + alpha + F + mu.  mu layout: mu[p*6 + axis*3 + c]
__global__ void flow_kernel(const float* __restrict__ x, const float* __restrict__ Hs,
                            float* __restrict__ mu) {
  int p = blockIdx.x * 256 + threadIdx.x;
  int px = p >> 9, py = p & 511;
  float syH0 = 0.f, syH1 = 0.f, syH2 = 0.f;
  float sxH0 = 0.f, sxH1 = 0.f, sxH2 = 0.f;
  float syX = 0.f, sxX = 0.f;
#pragma unroll
  for (int di = -1; di <= 1; ++di) {
#pragma unroll
    for (int dj = -1; dj <= 1; ++dj) {
      if (di == 0 && dj == 0) continue;
      int xi = px + di, yj = py + dj;
      if ((unsigned)xi >= 512u || (unsigned)yj >= 512u) continue;  // zero pad
      float wy = (float)di * ((dj == 0) ? 2.f : 1.f);
      float wx = (float)dj * ((di == 0) ? 2.f : 1.f);
      int q = (xi << 9) | yj;
      float h0 = Hs[q], h1 = Hs[NPIX + q], h2 = Hs[2 * NPIX + q];
      syH0 += wy * h0; syH1 += wy * h1; syH2 += wy * h2;
      sxH0 += wx * h0; sxH1 += wx * h1; sxH2 += wx * h2;
      float xs = x[(size_t)q * 3 + 0] + x[(size_t)q * 3 + 1] + x[(size_t)q * 3 + 2];
      syX += wy * xs; sxX += wx * xs;
    }
  }
  float cxp = (float)px + 0.5f, cyp = (float)py + 0.5f;
  float* mup = mu + (size_t)p * 6;
  float syH[3] = {syH0, syH1, syH2};
  float sxH[3] = {sxH0, sxH1, sxH2};
#pragma unroll
  for (int c = 0; c < 3; ++c) {
    float xc = x[(size_t)p * 3 + c];
    float tt = xc * 0.5f;
    float alpha = fminf(tt * tt, 1.0f);
    float F0 = syH[c] * (1.f - alpha) - syX * alpha;
    float F1 = sxH[c] * (1.f - alpha) - sxX * alpha;
    float m0 = cxp + fminf(fmaxf(0.2f * F0, -1.05f), 1.05f);
    float m1 = cyp + fminf(fmaxf(0.2f * F1, -1.05f), 1.05f);
    mup[c]     = fminf(fmaxf(m0, 0.95f), 511.05f);
    mup[3 + c] = fminf(fmaxf(m1, 0.95f), 511.05f);
  }
}

// 25-offset reintegration gather
__global__ void reintegrate_kernel(const float* __restrict__ x, const float* __restrict__ mu,
                                   float* __restrict__ out) {
  int p = blockIdx.x * 256 + threadIdx.x;
  int px = p >> 9, py = p & 511;
  float cx = (float)px + 0.5f, cy = (float)py + 0.5f;
  float a0 = 0.f, a1 = 0.f, a2 = 0.f;
#pragma unroll
  for (int dx = -2; dx <= 2; ++dx) {
    int qx = (px - dx + 512) & 511;
#pragma unroll
    for (int dy = -2; dy <= 2; ++dy) {
      int qy = (py - dy + 512) & 511;
      int q = (qx << 9) | qy;
      const float* muq = mu + (size_t)q * 6;
      const float* gq = x + (size_t)q * 3;
      float w;
      w = fminf(fmaxf(1.45f - fabsf(cx - muq[0]), 0.f), 1.f) *
          fminf(fmaxf(1.45f - fabsf(cy - muq[3]), 0.f), 1.f);
      a0 += gq[0] * w;
      w = fminf(fmaxf(1.45f - fabsf(cx - muq[1]), 0.f), 1.f) *
          fminf(fmaxf(1.45f - fabsf(cy - muq[4]), 0.f), 1.f);
      a1 += gq[1] * w;
      w = fminf(fmaxf(1.45f - fabsf(cx - muq[2]), 0.f), 1.f) *
          fminf(fmaxf(1.45f - fabsf(cy - muq[5]), 0.f), 1.f);
      a2 += gq[2] * w;
    }
  }
  const float inv_area = 0.27700831f;  // 1/(4*0.95^2)
  out[(size_t)p * 3 + 0] = a0 * inv_area;
  out[(size_t)p * 3 + 1] = a1 * inv_area;
  out[(size_t)p * 3 + 2] = a2 * inv_area;
}

extern "C" void kernel_launch(void* const* d_in, const int* in_sizes, int n_in,
                              void* d_out, int out_size, void* d_ws, size_t ws_size,
                              hipStream_t stream) {
  const float* x    = (const float*)d_in[0];
  const float* Ks   = (const float*)d_in[1];
  const float* m    = (const float*)d_in[2];
  const float* s    = (const float*)d_in[3];
  const float* h    = (const float*)d_in[4];
  const float* w_c1 = (const float*)d_in[5];
  const int*   c0   = (const int*)d_in[6];
  float* out = (float*)d_out;

  char* ws = (char*)d_ws;
  size_t off = 0;
  float* sums    = (float*)(ws + off); off += 1024;
  float* partial = (float*)(ws + off); off += 1024 * 16 * 4;
  float2* Ax   = (float2*)(ws + off); off += (size_t)3 * NPIX * 8;     // 6 MB
  float2* Ak   = (float2*)(ws + off); off += (size_t)NKER * NPIX * 8;  // 30 MB
  float*  Hs   = (float*)(ws + off);  off += (size_t)3 * NPIX * 4;     // 3 MB
  float*  mu   = (float*)(ws + off);  off += (size_t)6 * NPIX * 4;     // 6 MB

  ksum_partial<<<1024, 256, 0, stream>>>(Ks, partial);
  ksum_final<<<1, 256, 0, stream>>>(partial, sums);
  fft_rows_x<<<dim3(128, 3), 256, 0, stream>>>(x, Ax);
  fft_rows_k<<<dim3(128, NKER), 256, 0, stream>>>(Ks, sums, Ak);
  fused_cols<<<dim3(64, NKER), 512, 0, stream>>>(Ak, Ax, c0);
  irows_growth_combine<<<512, 256, 0, stream>>>(Ak, m, s, h, w_c1, Hs);
  flow_kernel<<<1024, 256, 0, stream>>>(x, Hs, mu);
  reintegrate_kernel<<<1024, 256, 0, stream>>>(x, mu, out);
}

// Round 5
// 174.151 us; speedup vs baseline: 4.0456x; 1.0403x over previous
//
#include <hip/hip_runtime.h>
#include <math.h>

#define NPIX 262144   // 512*512
#define NKER 15
#define PI_F 3.14159265358979323846f
#define CS 578        // wave scratch stride (float2): >= SK(511)=574, bank-skewed
#define SK(n) ((n) + ((n) >> 3))   // skewed LDS index: 4-way max conflicts

__device__ __forceinline__ float2 cadd(float2 a, float2 b) { return make_float2(a.x + b.x, a.y + b.y); }
__device__ __forceinline__ float2 csub(float2 a, float2 b) { return make_float2(a.x - b.x, a.y - b.y); }
__device__ __forceinline__ float2 cmul(float2 a, float2 b) {
  return make_float2(a.x * b.x - a.y * b.y, a.x * b.y + a.y * b.x);
}

// per-lane FFT roots: w1 = e^{-2pi i lane/512}, wh = e^{-2pi i (lane&~7)/512}
__device__ __forceinline__ void fft_roots(int lane, float2* w1, float2* wh) {
  float s, c;
  sincosf(-2.0f * PI_F * (float)lane / 512.0f, &s, &c);
  *w1 = make_float2(c, s);
  int h = lane & ~7;
  *wh = make_float2(__shfl(c, h, 64), __shfl(s, h, 64));
}

// 8-point DIF DFT in registers, natural-order outputs. INV => conjugate.
template <bool INV>
__device__ __forceinline__ void dft8(float2 a[8]) {
  const float R = 0.70710678118654752f;
  float2 t0 = cadd(a[0], a[4]), u0 = csub(a[0], a[4]);
  float2 t1 = cadd(a[1], a[5]), u1 = csub(a[1], a[5]);
  float2 t2 = cadd(a[2], a[6]), u2 = csub(a[2], a[6]);
  float2 t3 = cadd(a[3], a[7]), u3 = csub(a[3], a[7]);
  u1 = INV ? make_float2(R * (u1.x - u1.y), R * (u1.x + u1.y))
           : make_float2(R * (u1.x + u1.y), R * (u1.y - u1.x));
  u2 = INV ? make_float2(-u2.y, u2.x) : make_float2(u2.y, -u2.x);
  u3 = INV ? make_float2(-R * (u3.x + u3.y), R * (u3.x - u3.y))
           : make_float2(R * (u3.y - u3.x), -R * (u3.x + u3.y));
  float2 e0 = cadd(t0, t2), f0 = csub(t0, t2);
  float2 e1 = cadd(t1, t3), f1 = csub(t1, t3);
  f1 = INV ? make_float2(-f1.y, f1.x) : make_float2(f1.y, -f1.x);
  float2 g0 = cadd(u0, u2), h0 = csub(u0, u2);
  float2 g1 = cadd(u1, u3), h1 = csub(u1, u3);
  h1 = INV ? make_float2(-h1.y, h1.x) : make_float2(h1.y, -h1.x);
  a[0] = cadd(e0, e1); a[4] = csub(e0, e1);
  a[2] = cadd(f0, f1); a[6] = csub(f0, f1);
  a[1] = cadd(g0, g1); a[5] = csub(g0, g1);
  a[3] = cadd(h0, h1); a[7] = csub(h0, h1);
}

// 512-pt Stockham radix-8, 3 stages, one wave, 8 pts/thread.
// a[q] holds point (lane + 64q) in and out. buf = wave-private scratch (>=575 f2,
// SK layout). Twiddles from register recurrence (no LDS). No barriers needed.
template <bool INV>
__device__ __forceinline__ void fft512_r8(float2 a[8], float2* buf, int lane,
                                          float2 w1, float2 wh) {
  float2 wa = INV ? make_float2(w1.x, -w1.y) : w1;
  float2 wb = INV ? make_float2(wh.x, -wh.y) : wh;
  // stage m=1
  dft8<INV>(a);
  {
    float2 tq = wa;
    a[1] = cmul(a[1], tq);
#pragma unroll
    for (int q = 2; q < 8; ++q) { tq = cmul(tq, wa); a[q] = cmul(a[q], tq); }
  }
#pragma unroll
  for (int q = 0; q < 8; ++q) buf[9 * lane + q] = a[q];   // SK(8*lane+q)
  // stage m=8
#pragma unroll
  for (int q = 0; q < 8; ++q) a[q] = buf[SK(lane + 64 * q)];
  dft8<INV>(a);
  {
    float2 tq = wb;
    a[1] = cmul(a[1], tq);
#pragma unroll
    for (int q = 2; q < 8; ++q) { tq = cmul(tq, wb); a[q] = cmul(a[q], tq); }
  }
  int h = lane & ~7;
  int b2 = 9 * h + (lane - h);       // SK(8h+8q+(lane-h)) = 9h + 9q + (lane-h)
#pragma unroll
  for (int q = 0; q < 8; ++q) buf[b2 + 9 * q] = a[q];
  // stage m=64 (no twiddle)
#pragma unroll
  for (int q = 0; q < 8; ++q) a[q] = buf[SK(lane + 64 * q)];
  dft8<INV>(a);
}

// ---- ksum: block reduction (no global atomics) ----
__global__ void ksum_partial(const float* __restrict__ Ks, float* __restrict__ partial) {
  __shared__ float wsum[4][16];
  int p = blockIdx.x * 256 + threadIdx.x;
  const float* src = Ks + (size_t)p * NKER;
  float acc[NKER];
#pragma unroll
  for (int k = 0; k < NKER; ++k) acc[k] = src[k];
#pragma unroll
  for (int k = 0; k < NKER; ++k) {
#pragma unroll
    for (int off = 32; off > 0; off >>= 1) acc[k] += __shfl_down(acc[k], off, 64);
  }
  int wave = threadIdx.x >> 6;
  if ((threadIdx.x & 63) == 0) {
#pragma unroll
    for (int k = 0; k < NKER; ++k) wsum[wave][k] = acc[k];
  }
  __syncthreads();
  if (threadIdx.x < NKER) {
    int k = threadIdx.x;
    partial[blockIdx.x * 16 + k] = wsum[0][k] + wsum[1][k] + wsum[2][k] + wsum[3][k];
  }
}

__global__ void ksum_final(const float* __restrict__ partial, float* __restrict__ sums) {
  __shared__ float red[256];
  int t = threadIdx.x;
  int k = t & 15, g = t >> 4;
  float acc = 0.f;
  for (int b = g; b < 1024; b += 16) acc += partial[b * 16 + k];
  red[t] = acc;
  __syncthreads();
  if (t < 16) {
    float s = 0.f;
#pragma unroll
    for (int g2 = 0; g2 < 16; ++g2) s += red[g2 * 16 + t];
    sums[t] = s;
  }
}

// ---- row FFT of x: 4 waves/block, wave per row -> Ax[c][row][y] ----
__global__ void fft_rows_x(const float* __restrict__ x, float2* __restrict__ Ax) {
  __shared__ float2 scr[4][CS];
  int t = threadIdx.x, wave = t >> 6, lane = t & 63;
  int row = blockIdx.x * 4 + wave, c = blockIdx.y;
  float2 w1, wh;
  fft_roots(lane, &w1, &wh);
  float2 a[8];
#pragma unroll
  for (int q = 0; q < 8; ++q)
    a[q] = make_float2(x[((size_t)row * 512 + lane + 64 * q) * 3 + c], 0.f);
  fft512_r8<false>(a, &scr[wave][0], lane, w1, wh);
  float2* dst = Ax + (size_t)c * NPIX + (size_t)row * 512;
#pragma unroll
  for (int q = 0; q < 8; ++q) dst[lane + 64 * q] = a[q];
}

// ---- row FFT of fftshift(Ks[:,:,k]) / (sum*N^2) -> Ak[k][row][y] ----
// One block per row: stage the contiguous 30KB Ks row coalesced into LDS,
// then 4 waves cover the 15 kernels (stride-15-float LDS reads: conflict-free).
__global__ void fft_rows_k(const float* __restrict__ Ks, const float* __restrict__ sums,
                           float2* __restrict__ Ak) {
  __shared__ float krow[512 * NKER];   // 30720 B
  __shared__ float2 scr[4][CS];
  int t = threadIdx.x, wave = t >> 6, lane = t & 63;
  int row = blockIdx.x;
  int rs = (row + 256) & 511;
  const float2* src2 = (const float2*)(Ks + (size_t)rs * 512 * NKER);  // 3840 f2
  float2* krow2 = (float2*)krow;
#pragma unroll
  for (int i = 0; i < 15; ++i) krow2[t + 256 * i] = src2[t + 256 * i];
  __syncthreads();
  float2 w1, wh;
  fft_roots(lane, &w1, &wh);
  for (int ki = 0; ki < 4; ++ki) {
    int k = wave + 4 * ki;
    if (k >= NKER) break;
    float sc = 1.0f / (sums[k] * 262144.0f);
    float2 a[8];
#pragma unroll
    for (int q = 0; q < 8; ++q) {
      int ys = (lane + 64 * q + 256) & 511;
      a[q] = make_float2(krow[ys * NKER + k] * sc, 0.f);
    }
    fft512_r8<false>(a, &scr[wave][0], lane, w1, wh);
    float2* dst = Ak + (size_t)k * NPIX + (size_t)row * 512;
#pragma unroll
    for (int q = 0; q < 8; ++q) dst[lane + 64 * q] = a[q];
  }
}

// ---- fused column pass: colFFT(Ax[c0k]) (regs), colFFT(Ak), cmul, icolFFT ----
// 512 threads = 8 waves, wave per column; 8 adjacent columns per block.
__global__ void fused_cols(float2* __restrict__ Ak, const float2* __restrict__ Ax,
                           const int* __restrict__ c0) {
  __shared__ float2 buf[8 * CS];   // 36992 B -> 4 blocks/CU
  int t = threadIdx.x, col0 = blockIdx.x * 8, k = blockIdx.y;
  int c = t >> 6, lane = t & 63;
  float2 w1, wh;
  fft_roots(lane, &w1, &wh);
  int c0k = c0[k];
  const float2* bx = Ax + (size_t)c0k * NPIX;
  float2* bk = Ak + (size_t)k * NPIX;
  // stage Ax slab (coalesced global, skewed LDS rows)
#pragma unroll
  for (int u = 0; u < 8; ++u) {
    int idx = (u << 9) + t;
    int row = idx >> 3, cc = idx & 7;
    buf[cc * CS + SK(row)] = bx[(size_t)row * 512 + col0 + cc];
  }
  __syncthreads();
  float2 xh[8];
#pragma unroll
  for (int q = 0; q < 8; ++q) xh[q] = buf[c * CS + SK(lane + 64 * q)];
  fft512_r8<false>(xh, &buf[c * CS], lane, w1, wh);
  __syncthreads();
  // stage Ak slab
#pragma unroll
  for (int u = 0; u < 8; ++u) {
    int idx = (u << 9) + t;
    int row = idx >> 3, cc = idx & 7;
    buf[cc * CS + SK(row)] = bk[(size_t)row * 512 + col0 + cc];
  }
  __syncthreads();
  float2 a[8];
#pragma unroll
  for (int q = 0; q < 8; ++q) a[q] = buf[c * CS + SK(lane + 64 * q)];
  fft512_r8<false>(a, &buf[c * CS], lane, w1, wh);
#pragma unroll
  for (int q = 0; q < 8; ++q) a[q] = cmul(a[q], xh[q]);
  fft512_r8<true>(a, &buf[c * CS], lane, w1, wh);
#pragma unroll
  for (int q = 0; q < 8; ++q) buf[c * CS + SK(lane + 64 * q)] = a[q];
  __syncthreads();
  // coalesced store back to Ak
#pragma unroll
  for (int u = 0; u < 8; ++u) {
    int idx = (u << 9) + t;
    int row = idx >> 3, cc = idx & 7;
    bk[(size_t)row * 512 + col0 + cc] = buf[cc * CS + SK(row)];
  }
}

// ---- fused inverse row FFT + growth + w_c1 combine -> Hs[c][p] ----
__global__ void irows_growth_combine(const float2* __restrict__ Ak,
                                     const float* __restrict__ m, const float* __restrict__ s,
                                     const float* __restrict__ h, const float* __restrict__ w,
                                     float* __restrict__ Hs) {
  __shared__ float2 scr[4][CS];
  __shared__ float accL[4][3][512];
  __shared__ float mk[16], isk[16], hk[16], wk[16][3];
  int t = threadIdx.x, wave = t >> 6, lane = t & 63;
  int row = blockIdx.x;
  if (t < NKER) {
    mk[t] = m[t]; isk[t] = 1.0f / s[t]; hk[t] = h[t];
    wk[t][0] = w[t * 3 + 0]; wk[t][1] = w[t * 3 + 1]; wk[t][2] = w[t * 3 + 2];
  }
  __syncthreads();
  float2 w1, wh;
  fft_roots(lane, &w1, &wh);
  float acc[3][8];
#pragma unroll
  for (int cc = 0; cc < 3; ++cc)
#pragma unroll
    for (int q = 0; q < 8; ++q) acc[cc][q] = 0.f;
  int kbeg = wave * 4, kend = (wave == 3) ? 15 : kbeg + 4;
  for (int k = kbeg; k < kend; ++k) {
    const float2* src = Ak + (size_t)k * NPIX + (size_t)row * 512;
    float2 a[8];
#pragma unroll
    for (int q = 0; q < 8; ++q) a[q] = src[lane + 64 * q];
    fft512_r8<true>(a, &scr[wave][0], lane, w1, wh);
    float mm = mk[k], is = isk[k], hhk = hk[k];
    float w0 = wk[k][0], wv1 = wk[k][1], w2 = wk[k][2];
#pragma unroll
    for (int q = 0; q < 8; ++q) {
      float tt = (a[q].x - mm) * is;
      float g = (expf(-0.5f * tt * tt) * 2.0f - 1.0f) * hhk;
      acc[0][q] += g * w0; acc[1][q] += g * wv1; acc[2][q] += g * w2;
    }
  }
#pragma unroll
  for (int cc = 0; cc < 3; ++cc)
#pragma unroll
    for (int q = 0; q < 8; ++q) accL[wave][cc][lane + 64 * q] = acc[cc][q];
  __syncthreads();
#pragma unroll
  for (int cc = 0; cc < 3; ++cc) {
#pragma unroll
    for (int rep = 0; rep < 2; ++rep) {
      int p = t + (rep << 8);
      float v = accL[0][cc][p] + accL[1][cc][p] + accL[2][cc][p] + accL[3][cc][p];
      Hs[(size_t)cc * NPIX + (size_t)row * 512 + p] = v;
    }
  }
}

// sobel (zero pad) + alpha + F + mu.  mu layout: mu[p*6 + axis*3 + c]
__global__ void flow_kernel(const float* __restrict__ x, const float* __restrict__ Hs,
                            float* __restrict__ mu) {
  int p = blockIdx.x * 256 + threadIdx.x;
  int px = p >> 9, py = p & 511;
  float syH0 = 0.f, syH1 = 0.f, syH2 = 0.f;
  float sxH0 = 0.f, sxH1 = 0.f, sxH2 = 0.f;
  float syX = 0.f, sxX = 0.f;
#pragma unroll
  for (int di = -1; di <= 1; ++di) {
#pragma unroll
    for (int dj = -1; dj <= 1; ++dj) {
      if (di == 0 && dj == 0) continue;
      int xi = px + di, yj = py + dj;
      if ((unsigned)xi >= 512u || (unsigned)yj >= 512u) continue;  // zero pad
      float wy = (float)di * ((dj == 0) ? 2.f : 1.f);
      float wx = (float)dj * ((di == 0) ? 2.f : 1.f);
      int q = (xi << 9) | yj;
      float h0 = Hs[q], h1 = Hs[NPIX + q], h2 = Hs[2 * NPIX + q];
      syH0 += wy * h0; syH1 += wy * h1; syH2 += wy * h2;
      sxH0 += wx * h0; sxH1 += wx * h1; sxH2 += wx * h2;
      float xs = x[(size_t)q * 3 + 0] + x[(size_t)q * 3 + 1] + x[(size_t)q * 3 + 2];
      syX += wy * xs; sxX += wx * xs;
    }
  }
  float cxp = (float)px + 0.5f, cyp = (float)py + 0.5f;
  float* mup = mu + (size_t)p * 6;
  float syH[3] = {syH0, syH1, syH2};
  float sxH[3] = {sxH0, sxH1, sxH2};
#pragma unroll
  for (int c = 0; c < 3; ++c) {
    float xc = x[(size_t)p * 3 + c];
    float tt = xc * 0.5f;
    float alpha = fminf(tt * tt, 1.0f);
    float F0 = syH[c] * (1.f - alpha) - syX * alpha;
    float F1 = sxH[c] * (1.f - alpha) - sxX * alpha;
    float m0 = cxp + fminf(fmaxf(0.2f * F0, -1.05f), 1.05f);
    float m1 = cyp + fminf(fmaxf(0.2f * F1, -1.05f), 1.05f);
    mup[c]     = fminf(fmaxf(m0, 0.95f), 511.05f);
    mup[3 + c] = fminf(fmaxf(m1, 0.95f), 511.05f);
  }
}

// 25-offset reintegration gather
__global__ void reintegrate_kernel(const float* __restrict__ x, const float* __restrict__ mu,
                                   float* __restrict__ out) {
  int p = blockIdx.x * 256 + threadIdx.x;
  int px = p >> 9, py = p & 511;
  float cx = (float)px + 0.5f, cy = (float)py + 0.5f;
  float a0 = 0.f, a1 = 0.f, a2 = 0.f;
#pragma unroll
  for (int dx = -2; dx <= 2; ++dx) {
    int qx = (px - dx + 512) & 511;
#pragma unroll
    for (int dy = -2; dy <= 2; ++dy) {
      int qy = (py - dy + 512) & 511;
      int q = (qx << 9) | qy;
      const float* muq = mu + (size_t)q * 6;
      const float* gq = x + (size_t)q * 3;
      float w;
      w = fminf(fmaxf(1.45f - fabsf(cx - muq[0]), 0.f), 1.f) *
          fminf(fmaxf(1.45f - fabsf(cy - muq[3]), 0.f), 1.f);
      a0 += gq[0] * w;
      w = fminf(fmaxf(1.45f - fabsf(cx - muq[1]), 0.f), 1.f) *
          fminf(fmaxf(1.45f - fabsf(cy - muq[4]), 0.f), 1.f);
      a1 += gq[1] * w;
      w = fminf(fmaxf(1.45f - fabsf(cx - muq[2]), 0.f), 1.f) *
          fminf(fmaxf(1.45f - fabsf(cy - muq[5]), 0.f), 1.f);
      a2 += gq[2] * w;
    }
  }
  const float inv_area = 0.27700831f;  // 1/(4*0.95^2)
  out[(size_t)p * 3 + 0] = a0 * inv_area;
  out[(size_t)p * 3 + 1] = a1 * inv_area;
  out[(size_t)p * 3 + 2] = a2 * inv_area;
}

extern "C" void kernel_launch(void* const* d_in, const int* in_sizes, int n_in,
                              void* d_out, int out_size, void* d_ws, size_t ws_size,
                              hipStream_t stream) {
  const float* x    = (const float*)d_in[0];
  const float* Ks   = (const float*)d_in[1];
  const float* m    = (const float*)d_in[2];
  const float* s    = (const float*)d_in[3];
  const float* h    = (const float*)d_in[4];
  const float* w_c1 = (const float*)d_in[5];
  const int*   c0   = (const int*)d_in[6];
  float* out = (float*)d_out;

  char* ws = (char*)d_ws;
  size_t off = 0;
  float* sums    = (float*)(ws + off); off += 1024;
  float* partial = (float*)(ws + off); off += 1024 * 16 * 4;
  float2* Ax   = (float2*)(ws + off); off += (size_t)3 * NPIX * 8;     // 6 MB
  float2* Ak   = (float2*)(ws + off); off += (size_t)NKER * NPIX * 8;  // 30 MB
  float*  Hs   = (float*)(ws + off);  off += (size_t)3 * NPIX * 4;     // 3 MB
  float*  mu   = (float*)(ws + off);  off += (size_t)6 * NPIX * 4;     // 6 MB

  ksum_partial<<<1024, 256, 0, stream>>>(Ks, partial);
  ksum_final<<<1, 256, 0, stream>>>(partial, sums);
  fft_rows_x<<<dim3(128, 3), 256, 0, stream>>>(x, Ax);
  fft_rows_k<<<512, 256, 0, stream>>>(Ks, sums, Ak);
  fused_cols<<<dim3(64, NKER), 512, 0, stream>>>(Ak, Ax, c0);
  irows_growth_combine<<<512, 256, 0, stream>>>(Ak, m, s, h, w_c1, Hs);
  flow_kernel<<<1024, 256, 0, stream>>>(x, Hs, mu);
  reintegrate_kernel<<<1024, 256, 0, stream>>>(x, mu, out);
}

// Round 6
// 163.241 us; speedup vs baseline: 4.3160x; 1.0668x over previous
//
#include <hip/hip_runtime.h>
#include <math.h>

#define NPIX 262144   // 512*512
#define NKER 15
#define PI_F 3.14159265358979323846f
#define HW 264        // half-plane row stride (float2): 257 used, padded to 8
#define CS 578        // wave scratch stride (float2): >= SK(511)=574
#define SK(n) ((n) + ((n) >> 3))   // skewed LDS index: <=4-way conflicts

__device__ __forceinline__ float2 cadd(float2 a, float2 b) { return make_float2(a.x + b.x, a.y + b.y); }
__device__ __forceinline__ float2 csub(float2 a, float2 b) { return make_float2(a.x - b.x, a.y - b.y); }
__device__ __forceinline__ float2 cmul(float2 a, float2 b) {
  return make_float2(a.x * b.x - a.y * b.y, a.x * b.y + a.y * b.x);
}

// per-lane FFT roots: w1 = e^{-2pi i lane/512}, wh = e^{-2pi i (lane&~7)/512}
__device__ __forceinline__ void fft_roots(int lane, float2* w1, float2* wh) {
  float s, c;
  sincosf(-2.0f * PI_F * (float)lane / 512.0f, &s, &c);
  *w1 = make_float2(c, s);
  int h = lane & ~7;
  *wh = make_float2(__shfl(c, h, 64), __shfl(s, h, 64));
}

template <bool INV>
__device__ __forceinline__ void dft8(float2 a[8]) {
  const float R = 0.70710678118654752f;
  float2 t0 = cadd(a[0], a[4]), u0 = csub(a[0], a[4]);
  float2 t1 = cadd(a[1], a[5]), u1 = csub(a[1], a[5]);
  float2 t2 = cadd(a[2], a[6]), u2 = csub(a[2], a[6]);
  float2 t3 = cadd(a[3], a[7]), u3 = csub(a[3], a[7]);
  u1 = INV ? make_float2(R * (u1.x - u1.y), R * (u1.x + u1.y))
           : make_float2(R * (u1.x + u1.y), R * (u1.y - u1.x));
  u2 = INV ? make_float2(-u2.y, u2.x) : make_float2(u2.y, -u2.x);
  u3 = INV ? make_float2(-R * (u3.x + u3.y), R * (u3.x - u3.y))
           : make_float2(R * (u3.y - u3.x), -R * (u3.x + u3.y));
  float2 e0 = cadd(t0, t2), f0 = csub(t0, t2);
  float2 e1 = cadd(t1, t3), f1 = csub(t1, t3);
  f1 = INV ? make_float2(-f1.y, f1.x) : make_float2(f1.y, -f1.x);
  float2 g0 = cadd(u0, u2), h0 = csub(u0, u2);
  float2 g1 = cadd(u1, u3), h1 = csub(u1, u3);
  h1 = INV ? make_float2(-h1.y, h1.x) : make_float2(h1.y, -h1.x);
  a[0] = cadd(e0, e1); a[4] = csub(e0, e1);
  a[2] = cadd(f0, f1); a[6] = csub(f0, f1);
  a[1] = cadd(g0, g1); a[5] = csub(g0, g1);
  a[3] = cadd(h0, h1); a[7] = csub(h0, h1);
}

// 512-pt Stockham radix-8, one wave, 8 pts/thread, a[q] = point (lane+64q).
// buf = wave-private SK-layout scratch. Twiddles via register recurrence.
template <bool INV>
__device__ __forceinline__ void fft512_r8(float2 a[8], float2* buf, int lane,
                                          float2 w1, float2 wh) {
  float2 wa = INV ? make_float2(w1.x, -w1.y) : w1;
  float2 wb = INV ? make_float2(wh.x, -wh.y) : wh;
  dft8<INV>(a);
  {
    float2 tq = wa;
    a[1] = cmul(a[1], tq);
#pragma unroll
    for (int q = 2; q < 8; ++q) { tq = cmul(tq, wa); a[q] = cmul(a[q], tq); }
  }
#pragma unroll
  for (int q = 0; q < 8; ++q) buf[9 * lane + q] = a[q];
#pragma unroll
  for (int q = 0; q < 8; ++q) a[q] = buf[SK(lane + 64 * q)];
  dft8<INV>(a);
  {
    float2 tq = wb;
    a[1] = cmul(a[1], tq);
#pragma unroll
    for (int q = 2; q < 8; ++q) { tq = cmul(tq, wb); a[q] = cmul(a[q], tq); }
  }
  int h = lane & ~7;
  int b2 = 9 * h + (lane - h);
#pragma unroll
  for (int q = 0; q < 8; ++q) buf[b2 + 9 * q] = a[q];
#pragma unroll
  for (int q = 0; q < 8; ++q) a[q] = buf[SK(lane + 64 * q)];
  dft8<INV>(a);
}

// After packed FFT Z of (rowA + i rowB): write half-plane spectra of both rows.
// Uses buf (wave-private) for the conjugate mirror. d0/d1 = row bases (HW stride).
__device__ __forceinline__ void split_store_halfplane(float2 a[8], float2* buf, int lane,
                                                      float2* d0, float2* d1) {
#pragma unroll
  for (int q = 0; q < 8; ++q) buf[SK(lane + 64 * q)] = a[q];
#pragma unroll
  for (int q = 0; q < 4; ++q) {
    int v = lane + 64 * q;
    int mir = (512 - v) & 511;
    float2 P = a[q];
    float2 Qc = buf[SK(mir)];
    float2 Q = make_float2(Qc.x, -Qc.y);       // conj(Z[-v])
    d0[v] = make_float2(0.5f * (P.x + Q.x), 0.5f * (P.y + Q.y));
    d1[v] = make_float2(0.5f * (P.y - Q.y), -0.5f * (P.x - Q.x));
  }
  if (lane == 0) {  // v = 256
    float2 P = a[4];
    d0[256] = make_float2(P.x, 0.f);
    d1[256] = make_float2(P.y, 0.f);
  }
}

// ---- ksum: block reduction (no global atomics) ----
__global__ void ksum_partial(const float* __restrict__ Ks, float* __restrict__ partial) {
  __shared__ float wsum[4][16];
  int p = blockIdx.x * 256 + threadIdx.x;
  const float* src = Ks + (size_t)p * NKER;
  float acc[NKER];
#pragma unroll
  for (int k = 0; k < NKER; ++k) acc[k] = src[k];
#pragma unroll
  for (int k = 0; k < NKER; ++k) {
#pragma unroll
    for (int off = 32; off > 0; off >>= 1) acc[k] += __shfl_down(acc[k], off, 64);
  }
  int wave = threadIdx.x >> 6;
  if ((threadIdx.x & 63) == 0) {
#pragma unroll
    for (int k = 0; k < NKER; ++k) wsum[wave][k] = acc[k];
  }
  __syncthreads();
  if (threadIdx.x < NKER) {
    int k = threadIdx.x;
    partial[blockIdx.x * 16 + k] = wsum[0][k] + wsum[1][k] + wsum[2][k] + wsum[3][k];
  }
}

__global__ void ksum_final(const float* __restrict__ partial, float* __restrict__ sums) {
  __shared__ float red[256];
  int t = threadIdx.x;
  int k = t & 15, g = t >> 4;
  float acc = 0.f;
  for (int b = g; b < 1024; b += 16) acc += partial[b * 16 + k];
  red[t] = acc;
  __syncthreads();
  if (t < 16) {
    float s = 0.f;
#pragma unroll
    for (int g2 = 0; g2 < 16; ++g2) s += red[g2 * 16 + t];
    sums[t] = s;
  }
}

// ---- R2C row FFT of x: pack rows (r, r+256) -> AxH[c][row][v], v=0..256 ----
__global__ void fft_rows_x(const float* __restrict__ x, float2* __restrict__ AxH) {
  __shared__ float2 scr[4][CS];
  int t = threadIdx.x, wave = t >> 6, lane = t & 63;
  int rp = blockIdx.x * 4 + wave;   // 0..255
  int c = blockIdx.y;
  int r0 = rp, r1 = rp + 256;
  float2 w1, wh;
  fft_roots(lane, &w1, &wh);
  float2 a[8];
#pragma unroll
  for (int q = 0; q < 8; ++q) {
    int y = lane + 64 * q;
    a[q] = make_float2(x[((size_t)r0 * 512 + y) * 3 + c],
                       x[((size_t)r1 * 512 + y) * 3 + c]);
  }
  fft512_r8<false>(a, &scr[wave][0], lane, w1, wh);
  float2* d0 = AxH + ((size_t)c * 512 + r0) * HW;
  float2* d1 = AxH + ((size_t)c * 512 + r1) * HW;
  split_store_halfplane(a, &scr[wave][0], lane, d0, d1);
}

// ---- R2C row FFT of fftshift(Ks)/norm: pack rows (b, b+256) for all 15 k ----
// fftshift: output row b sources Ks row b+256 and vice versa; column shift in ys.
__global__ void fft_rows_k(const float* __restrict__ Ks, const float* __restrict__ sums,
                           float2* __restrict__ AkH) {
  __shared__ float krowA[512 * NKER];   // source for output row b   (= Ks row b+256)
  __shared__ float krowB[512 * NKER];   // source for output row b+256 (= Ks row b)
  __shared__ float2 scr[8][CS];
  int t = threadIdx.x, wave = t >> 6, lane = t & 63;
  int b = blockIdx.x;                   // 0..255
  const float2* sA = (const float2*)(Ks + (size_t)(b + 256) * 512 * NKER);
  const float2* sB = (const float2*)(Ks + (size_t)b * 512 * NKER);
  float2* kA2 = (float2*)krowA;
  float2* kB2 = (float2*)krowB;
  for (int i = t; i < 3840; i += 512) { kA2[i] = sA[i]; kB2[i] = sB[i]; }
  __syncthreads();
  float2 w1, wh;
  fft_roots(lane, &w1, &wh);
  for (int ki = 0; ki < 2; ++ki) {
    int k = wave + 8 * ki;
    if (k >= NKER) break;
    float sc = 1.0f / (sums[k] * 262144.0f);
    float2 a[8];
#pragma unroll
    for (int q = 0; q < 8; ++q) {
      int ys = (lane + 64 * q + 256) & 511;
      a[q] = make_float2(krowA[ys * NKER + k] * sc, krowB[ys * NKER + k] * sc);
    }
    fft512_r8<false>(a, &scr[wave][0], lane, w1, wh);
    float2* d0 = AkH + ((size_t)k * 512 + b) * HW;
    float2* d1 = AkH + ((size_t)k * 512 + b + 256) * HW;
    split_store_halfplane(a, &scr[wave][0], lane, d0, d1);
  }
}

// ---- fused column pass on the half-plane: 33 slabs of 8 columns ----
__global__ void fused_cols(float2* __restrict__ AkH, const float2* __restrict__ AxH,
                           const int* __restrict__ c0) {
  __shared__ float2 buf[8 * CS];   // 36992 B
  int t = threadIdx.x, col0 = blockIdx.x * 8, k = blockIdx.y;
  int c = t >> 6, lane = t & 63;
  float2 w1, wh;
  fft_roots(lane, &w1, &wh);
  int c0k = c0[k];
  const float2* bx = AxH + (size_t)c0k * 512 * HW;
  float2* bk = AkH + (size_t)k * 512 * HW;
#pragma unroll
  for (int u = 0; u < 8; ++u) {
    int idx = (u << 9) + t;
    int row = idx >> 3, cc = idx & 7;
    buf[cc * CS + SK(row)] = bx[(size_t)row * HW + col0 + cc];
  }
  __syncthreads();
  float2 xh[8];
#pragma unroll
  for (int q = 0; q < 8; ++q) xh[q] = buf[c * CS + SK(lane + 64 * q)];
  fft512_r8<false>(xh, &buf[c * CS], lane, w1, wh);
  __syncthreads();
#pragma unroll
  for (int u = 0; u < 8; ++u) {
    int idx = (u << 9) + t;
    int row = idx >> 3, cc = idx & 7;
    buf[cc * CS + SK(row)] = bk[(size_t)row * HW + col0 + cc];
  }
  __syncthreads();
  float2 a[8];
#pragma unroll
  for (int q = 0; q < 8; ++q) a[q] = buf[c * CS + SK(lane + 64 * q)];
  fft512_r8<false>(a, &buf[c * CS], lane, w1, wh);
#pragma unroll
  for (int q = 0; q < 8; ++q) a[q] = cmul(a[q], xh[q]);
  fft512_r8<true>(a, &buf[c * CS], lane, w1, wh);
#pragma unroll
  for (int q = 0; q < 8; ++q) buf[c * CS + SK(lane + 64 * q)] = a[q];
  __syncthreads();
#pragma unroll
  for (int u = 0; u < 8; ++u) {
    int idx = (u << 9) + t;
    int row = idx >> 3, cc = idx & 7;
    bk[(size_t)row * HW + col0 + cc] = buf[cc * CS + SK(row)];
  }
}

// ---- C2R inverse row FFT + growth + combine, 2 kernels packed per FFT ----
// slot s: k1=2s, k2=2s+1 (s=7 single). Wave w handles slots {w, w+4}.
__global__ void irows_growth_combine(const float2* __restrict__ AkH,
                                     const float* __restrict__ m, const float* __restrict__ s,
                                     const float* __restrict__ h, const float* __restrict__ w,
                                     float* __restrict__ Hs) {
  __shared__ float2 scr[4][CS];
  __shared__ float accL[4][3][512];
  __shared__ float mk[16], isk[16], hk[16], wk[16][3];
  int t = threadIdx.x, wave = t >> 6, lane = t & 63;
  int row = blockIdx.x;
  if (t < NKER) {
    mk[t] = m[t]; isk[t] = 1.0f / s[t]; hk[t] = h[t];
    wk[t][0] = w[t * 3 + 0]; wk[t][1] = w[t * 3 + 1]; wk[t][2] = w[t * 3 + 2];
  }
  __syncthreads();
  float2 w1, wh;
  fft_roots(lane, &w1, &wh);
  float acc[3][8];
#pragma unroll
  for (int cc = 0; cc < 3; ++cc)
#pragma unroll
    for (int q = 0; q < 8; ++q) acc[cc][q] = 0.f;
  for (int si = 0; si < 2; ++si) {
    int slot = wave + 4 * si;
    int k1 = 2 * slot, k2 = 2 * slot + 1;
    bool dual = (k2 < NKER);
    const float2* p1 = AkH + ((size_t)k1 * 512 + row) * HW;
    const float2* p2 = AkH + ((size_t)(dual ? k2 : k1) * 512 + row) * HW;
    float2 a[8];
#pragma unroll
    for (int q = 0; q < 8; ++q) {
      int v = lane + 64 * q;
      if (v <= 256) {
        float2 A1 = p1[v];
        float2 A2 = dual ? p2[v] : make_float2(0.f, 0.f);
        a[q] = make_float2(A1.x - A2.y, A1.y + A2.x);          // A1 + i*A2
      } else {
        int mi = 512 - v;
        float2 A1 = p1[mi];
        float2 A2 = dual ? p2[mi] : make_float2(0.f, 0.f);
        a[q] = make_float2(A1.x + A2.y, -A1.y + A2.x);         // conj(A1) + i*conj(A2)
      }
    }
    fft512_r8<true>(a, &scr[wave][0], lane, w1, wh);
    float m1 = mk[k1], i1 = isk[k1], h1 = hk[k1];
    float w10 = wk[k1][0], w11 = wk[k1][1], w12 = wk[k1][2];
#pragma unroll
    for (int q = 0; q < 8; ++q) {
      float tt = (a[q].x - m1) * i1;
      float g = (expf(-0.5f * tt * tt) * 2.0f - 1.0f) * h1;
      acc[0][q] += g * w10; acc[1][q] += g * w11; acc[2][q] += g * w12;
    }
    if (dual) {
      float m2 = mk[k2], i2 = isk[k2], h2 = hk[k2];
      float w20 = wk[k2][0], w21 = wk[k2][1], w22 = wk[k2][2];
#pragma unroll
      for (int q = 0; q < 8; ++q) {
        float tt = (a[q].y - m2) * i2;
        float g = (expf(-0.5f * tt * tt) * 2.0f - 1.0f) * h2;
        acc[0][q] += g * w20; acc[1][q] += g * w21; acc[2][q] += g * w22;
      }
    }
  }
#pragma unroll
  for (int cc = 0; cc < 3; ++cc)
#pragma unroll
    for (int q = 0; q < 8; ++q) accL[wave][cc][lane + 64 * q] = acc[cc][q];
  __syncthreads();
#pragma unroll
  for (int cc = 0; cc < 3; ++cc) {
#pragma unroll
    for (int rep = 0; rep < 2; ++rep) {
      int p = t + (rep << 8);
      float v = accL[0][cc][p] + accL[1][cc][p] + accL[2][cc][p] + accL[3][cc][p];
      Hs[(size_t)cc * NPIX + (size_t)row * 512 + p] = v;
    }
  }
}

// sobel (zero pad) + alpha + F + mu.  mu layout: mu[p*6 + axis*3 + c]
__global__ void flow_kernel(const float* __restrict__ x, const float* __restrict__ Hs,
                            float* __restrict__ mu) {
  int p = blockIdx.x * 256 + threadIdx.x;
  int px = p >> 9, py = p & 511;
  float syH0 = 0.f, syH1 = 0.f, syH2 = 0.f;
  float sxH0 = 0.f, sxH1 = 0.f, sxH2 = 0.f;
  float syX = 0.f, sxX = 0.f;
#pragma unroll
  for (int di = -1; di <= 1; ++di) {
#pragma unroll
    for (int dj = -1; dj <= 1; ++dj) {
      if (di == 0 && dj == 0) continue;
      int xi = px + di, yj = py + dj;
      if ((unsigned)xi >= 512u || (unsigned)yj >= 512u) continue;  // zero pad
      float wy = (float)di * ((dj == 0) ? 2.f : 1.f);
      float wx = (float)dj * ((di == 0) ? 2.f : 1.f);
      int q = (xi << 9) | yj;
      float h0 = Hs[q], h1 = Hs[NPIX + q], h2 = Hs[2 * NPIX + q];
      syH0 += wy * h0; syH1 += wy * h1; syH2 += wy * h2;
      sxH0 += wx * h0; sxH1 += wx * h1; sxH2 += wx * h2;
      float xs = x[(size_t)q * 3 + 0] + x[(size_t)q * 3 + 1] + x[(size_t)q * 3 + 2];
      syX += wy * xs; sxX += wx * xs;
    }
  }
  float cxp = (float)px + 0.5f, cyp = (float)py + 0.5f;
  float* mup = mu + (size_t)p * 6;
  float syH[3] = {syH0, syH1, syH2};
  float sxH[3] = {sxH0, sxH1, sxH2};
#pragma unroll
  for (int c = 0; c < 3; ++c) {
    float xc = x[(size_t)p * 3 + c];
    float tt = xc * 0.5f;
    float alpha = fminf(tt * tt, 1.0f);
    float F0 = syH[c] * (1.f - alpha) - syX * alpha;
    float F1 = sxH[c] * (1.f - alpha) - sxX * alpha;
    float m0 = cxp + fminf(fmaxf(0.2f * F0, -1.05f), 1.05f);
    float m1 = cyp + fminf(fmaxf(0.2f * F1, -1.05f), 1.05f);
    mup[c]     = fminf(fmaxf(m0, 0.95f), 511.05f);
    mup[3 + c] = fminf(fmaxf(m1, 0.95f), 511.05f);
  }
}

// 25-offset reintegration gather
__global__ void reintegrate_kernel(const float* __restrict__ x, const float* __restrict__ mu,
                                   float* __restrict__ out) {
  int p = blockIdx.x * 256 + threadIdx.x;
  int px = p >> 9, py = p & 511;
  float cx = (float)px + 0.5f, cy = (float)py + 0.5f;
  float a0 = 0.f, a1 = 0.f, a2 = 0.f;
#pragma unroll
  for (int dx = -2; dx <= 2; ++dx) {
    int qx = (px - dx + 512) & 511;
#pragma unroll
    for (int dy = -2; dy <= 2; ++dy) {
      int qy = (py - dy + 512) & 511;
      int q = (qx << 9) | qy;
      const float* muq = mu + (size_t)q * 6;
      const float* gq = x + (size_t)q * 3;
      float w;
      w = fminf(fmaxf(1.45f - fabsf(cx - muq[0]), 0.f), 1.f) *
          fminf(fmaxf(1.45f - fabsf(cy - muq[3]), 0.f), 1.f);
      a0 += gq[0] * w;
      w = fminf(fmaxf(1.45f - fabsf(cx - muq[1]), 0.f), 1.f) *
          fminf(fmaxf(1.45f - fabsf(cy - muq[4]), 0.f), 1.f);
      a1 += gq[1] * w;
      w = fminf(fmaxf(1.45f - fabsf(cx - muq[2]), 0.f), 1.f) *
          fminf(fmaxf(1.45f - fabsf(cy - muq[5]), 0.f), 1.f);
      a2 += gq[2] * w;
    }
  }
  const float inv_area = 0.27700831f;  // 1/(4*0.95^2)
  out[(size_t)p * 3 + 0] = a0 * inv_area;
  out[(size_t)p * 3 + 1] = a1 * inv_area;
  out[(size_t)p * 3 + 2] = a2 * inv_area;
}

extern "C" void kernel_launch(void* const* d_in, const int* in_sizes, int n_in,
                              void* d_out, int out_size, void* d_ws, size_t ws_size,
                              hipStream_t stream) {
  const float* x    = (const float*)d_in[0];
  const float* Ks   = (const float*)d_in[1];
  const float* m    = (const float*)d_in[2];
  const float* s    = (const float*)d_in[3];
  const float* h    = (const float*)d_in[4];
  const float* w_c1 = (const float*)d_in[5];
  const int*   c0   = (const int*)d_in[6];
  float* out = (float*)d_out;

  char* ws = (char*)d_ws;
  size_t off = 0;
  float* sums    = (float*)(ws + off); off += 1024;
  float* partial = (float*)(ws + off); off += 1024 * 16 * 4;
  float2* AxH  = (float2*)(ws + off); off += (size_t)3 * 512 * HW * 8;    // 3.2 MB
  float2* AkH  = (float2*)(ws + off); off += (size_t)NKER * 512 * HW * 8; // 16.2 MB
  float*  Hs   = (float*)(ws + off);  off += (size_t)3 * NPIX * 4;        // 3 MB
  float*  mu   = (float*)(ws + off);  off += (size_t)6 * NPIX * 4;        // 6 MB

  ksum_partial<<<1024, 256, 0, stream>>>(Ks, partial);
  ksum_final<<<1, 256, 0, stream>>>(partial, sums);
  fft_rows_x<<<dim3(64, 3), 256, 0, stream>>>(x, AxH);
  fft_rows_k<<<256, 512, 0, stream>>>(Ks, sums, AkH);
  fused_cols<<<dim3(33, NKER), 512, 0, stream>>>(AkH, AxH, c0);
  irows_growth_combine<<<512, 256, 0, stream>>>(AkH, m, s, h, w_c1, Hs);
  flow_kernel<<<1024, 256, 0, stream>>>(x, Hs, mu);
  reintegrate_kernel<<<1024, 256, 0, stream>>>(x, mu, out);
}